// Round 9
// baseline (946.751 us; speedup 1.0000x reference)
//
#include <hip/hip_runtime.h>
#include <math.h>

#define NSAMP 8192   // one block per sample

// LDS padding strides
#define WS4  5    // [32][4] weights
#define HS   21   // h1/h2 row stride (logical 20)
#define DVS  61   // dv matrix row stride (logical 60)

// ---------------------------------------------------------------- helpers

__device__ __forceinline__ void knn_compute(const float* xls, int C3, float* dls, int* idxls, int l)
{
  if (l < 25) {
    int m = l / 5, n = l % 5;
    float acc = 0.f;
    for (int r = 0; r < C3; ++r) acc += xls[r * 5 + m] * xls[r * 5 + n];
    dls[l] = acc;  // inner
  }
  __syncthreads();
  float dm = 0.f, dn = 0.f, inn = 0.f;
  if (l < 25) { int m = l / 5, n = l % 5; dm = dls[m * 5 + m]; dn = dls[n * 5 + n]; inn = dls[l]; }
  __syncthreads();
  if (l < 25) dls[l] = 2.f * inn - dm - dn;
  __syncthreads();
  if (l < 5) {
    int m = l; unsigned chosen = 0u;
    for (int kk = 0; kk < 4; ++kk) {
      float best = -3.4e38f; int bi = 0;
      for (int n = 0; n < 5; ++n) {
        if ((chosen >> n) & 1u) continue;
        float v = dls[m * 5 + n];
        if (v > best) { best = v; bi = n; }
      }
      idxls[m * 4 + kk] = bi;
      chosen |= (1u << bi);
    }
  }
  __syncthreads();
}

template<bool WD>
__device__ __forceinline__ void feat_pd2(const float* xls, const int* idxls,
    const float* Wf, const float* Wd, int o, int m, int kk, float* p, float* d)
{
  const int nb = idxls[m * 4 + kk];
  const float* wf = Wf + o * WS4;
  const float* wd = WD ? (Wd + o * WS4) : wf;
  for (int c = 0; c < 2; ++c) {
    float wfc = wf[c];
    float wdc = WD ? wd[c] : 0.f;
    #pragma unroll
    for (int j = 0; j < 3; ++j) {
      float v = xls[c * 15 + j * 5 + nb] - xls[c * 15 + j * 5 + m];
      p[j] += wfc * v;
      if (WD) d[j] += wdc * v;
    }
  }
  for (int c = 0; c < 2; ++c) {
    float wfc = wf[2 + c];
    float wdc = WD ? wd[2 + c] : 0.f;
    #pragma unroll
    for (int j = 0; j < 3; ++j) {
      float v = xls[c * 15 + j * 5 + m];
      p[j] += wfc * v;
      if (WD) d[j] += wdc * v;
    }
  }
}

__device__ __forceinline__ void lrelu3(const float* p, const float* d, float nrm,
    float mean, float rstd, float g, float b, float* out)
{
  float nbn = g * (nrm - mean) * rstd + b;
  float s = nbn / nrm;
  float pb0 = p[0] * s, pb1 = p[1] * s, pb2 = p[2] * s;
  float dot = pb0 * d[0] + pb1 * d[1] + pb2 * d[2];
  if (dot >= 0.f) { out[0] = pb0; out[1] = pb1; out[2] = pb2; }
  else {
    float dsq = d[0] * d[0] + d[1] * d[1] + d[2] * d[2];
    float f = 0.8f * (dot / (dsq + 1e-6f));
    out[0] = pb0 - f * d[0]; out[1] = pb1 - f * d[1]; out[2] = pb2 - f * d[2];
  }
}

__device__ __forceinline__ void load_x_sample(const float* nf, const float* noise, int s, int l, float* xls)
{
  if (l < 30) {
    int c = l / 15, j = (l / 5) % 3, m = l % 5, b = s >> 6;
    xls[l] = nf[((b * 5 + m) * 3 + j) * 2 + c] + noise[(((size_t)s * 5 + m) * 3 + j) * 2 + c];
  }
}

// cooperative dv matrix: dv[o][j*20 + col] = sum_c W[o][c] * H[(c*3+j)*HS + col]
// lane (o=l>>1, hh=l&1) computes cols hh*10..hh*10+9 per j. c ascending (order-exact).
__device__ __forceinline__ void pool_dv_build(const float* Wg, const float* H, float* dvls, int o, int hh)
{
  const float* wrow = Wg + o * 32;
  for (int j = 0; j < 3; ++j) {
    float acc[10];
    #pragma unroll
    for (int r = 0; r < 10; ++r) acc[r] = 0.f;
    for (int c = 0; c < 32; ++c) {
      float wc = wrow[c];
      const float* hrow = H + (c * 3 + j) * HS + hh * 10;
      #pragma unroll
      for (int r = 0; r < 10; ++r) acc[r] += wc * hrow[r];
    }
    #pragma unroll
    for (int r = 0; r < 10; ++r) dvls[o * DVS + j * 20 + hh * 10 + r] = acc[r];
  }
}

// ---------------------------------------------------------------- kernels

__global__ __launch_bounds__(64) void k_l1_pass1(const float* nf, const float* noise,
    const float* Wf1, double* part)
{
  __shared__ float xls[30], dls[25], wf[32 * WS4];
  __shared__ int idxls[20];
  int l = threadIdx.x;
  for (int r = l; r < 128; r += 64) wf[(r >> 2) * WS4 + (r & 3)] = Wf1[r];
  int o = l >> 1, hh = l & 1;
  double accS = 0, accQ = 0;
  int s = blockIdx.x;
  __syncthreads();
  load_x_sample(nf, noise, s, l, xls);
  __syncthreads();
  knn_compute(xls, 6, dls, idxls, l);
  for (int t = 0; t < 10; ++t) {
    int e = hh * 10 + t; int m = e >> 2, kk = e & 3;
    float p[3] = {0, 0, 0}, dum[3];
    feat_pd2<false>(xls, idxls, wf, wf, o, m, kk, p, dum);
    float nrm = sqrtf(p[0] * p[0] + p[1] * p[1] + p[2] * p[2]) + 1e-6f;
    accS += nrm; accQ += (double)nrm * (double)nrm;
  }
  double oS = accS + __shfl_down(accS, 1, 64);
  double oQ = accQ + __shfl_down(accQ, 1, 64);
  if (hh == 0) {
    part[((size_t)s * 32 + o) * 2 + 0] = oS;
    part[((size_t)s * 32 + o) * 2 + 1] = oQ;
  }
}

// two-stage deterministic reduce
__global__ __launch_bounds__(64) void k_red1(const double* part, double* red1, int C)
{
  int p = threadIdx.x, b = blockIdx.x;
  double acc = 0;
  if (p < 2 * C) {
    int o = p >> 1, q = p & 1;
    for (int g = b * 128; g < (b + 1) * 128; ++g)
      acc += part[((size_t)g * C + o) * 2 + q];
  }
  red1[b * 64 + p] = acc;
}

__global__ __launch_bounds__(64) void k_red1f(const float* part, double* red1, int C)
{
  int p = threadIdx.x, b = blockIdx.x;
  double acc = 0;
  if (p < 2 * C) {
    int o = p >> 1, q = p & 1;
    for (int g = b * 128; g < (b + 1) * 128; ++g)
      acc += (double)part[((size_t)g * C + o) * 2 + q];
  }
  red1[b * 64 + p] = acc;
}

__global__ __launch_bounds__(64) void k_red2(const double* red1, float* stats, int C, float count)
{
  __shared__ double tot[64];
  int p = threadIdx.x;
  double a = 0;
  if (p < 2 * C) for (int b = 0; b < 64; ++b) a += red1[b * 64 + p];
  tot[p] = a;
  __syncthreads();
  if (p < C) {
    double sum = tot[p * 2 + 0], ssq = tot[p * 2 + 1];
    double mean = sum / (double)count;
    double var = ssq / (double)count - mean * mean;
    stats[p * 2 + 0] = (float)mean;
    stats[p * 2 + 1] = (float)(1.0 / sqrt(var + 1e-5));
  }
}

// layer1 pass2 (h1, maxpool->x1) + layer2 pass1 stats via A/B factorization
__global__ __launch_bounds__(64, 4) void k_l1_pass2(const float* nf, const float* noise,
    const float* Wf1g, const float* Wd1g, const float* g1, const float* b1, const float* st1,
    const float* Wp1g, const float* Wf2g, float* X1, double* part)
{
  __shared__ float xls[30], dls[25], h1[96 * HS], x1ls[480];
  __shared__ float wf1[32 * WS4], wd1[32 * WS4];
  __shared__ float pool[32 * DVS];   // dv matrix (maxpool), then AB2[960] (A/B stats)
  __shared__ float gls[32], bls[32], stls[64];
  __shared__ int idxls[20], idx2[20];
  int l = threadIdx.x;
  for (int r = l; r < 128; r += 64) { int q = (r >> 2) * WS4 + (r & 3); wf1[q] = Wf1g[r]; wd1[q] = Wd1g[r]; }
  if (l < 32) { gls[l] = g1[l]; bls[l] = b1[l]; }
  if (l < 64) stls[l] = st1[l];
  int o = l >> 1, hh = l & 1;
  double accS = 0, accQ = 0;
  int s = blockIdx.x;
  __syncthreads();
  load_x_sample(nf, noise, s, l, xls);
  __syncthreads();
  knn_compute(xls, 6, dls, idxls, l);
  {
    float mean = stls[o * 2], rstd = stls[o * 2 + 1], gg = gls[o], bb = bls[o];
    for (int t = 0; t < 10; ++t) {
      int e = hh * 10 + t; int m = e >> 2, kk = e & 3;
      float p[3] = {0, 0, 0}, dd[3] = {0, 0, 0};
      feat_pd2<true>(xls, idxls, wf1, wd1, o, m, kk, p, dd);
      float nrm = sqrtf(p[0] * p[0] + p[1] * p[1] + p[2] * p[2]) + 1e-6f;
      float outv[3];
      lrelu3(p, dd, nrm, mean, rstd, gg, bb, outv);
      h1[(o * 3 + 0) * HS + m * 4 + kk] = outv[0];
      h1[(o * 3 + 1) * HS + m * 4 + kk] = outv[1];
      h1[(o * 3 + 2) * HS + m * 4 + kk] = outv[2];
    }
  }
  __syncthreads();
  pool_dv_build(Wp1g, h1, pool, o, hh);
  __syncthreads();
  for (int t = 0; t < 3; ++t) {
    int task = t * 64 + l;
    if (task < 160) {
      int oo = task & 31, m = task >> 5;
      float best = -3.4e38f; int bi = 0;
      for (int kk = 0; kk < 4; ++kk) {
        float acc = 0.f;
        for (int j = 0; j < 3; ++j)
          acc += h1[(oo * 3 + j) * HS + m * 4 + kk] * pool[oo * DVS + j * 20 + m * 4 + kk];
        if (acc > best) { best = acc; bi = kk; }
      }
      for (int j = 0; j < 3; ++j) {
        float v = h1[(oo * 3 + j) * HS + m * 4 + bi];
        x1ls[(oo * 3 + j) * 5 + m] = v;
        X1[(size_t)s * 480 + (oo * 3 + j) * 5 + m] = v;
      }
    }
  }
  __syncthreads();
  knn_compute(x1ls, 96, dls, idx2, l);   // internal barriers separate pool reuse
  {
    float acc[15];
    #pragma unroll
    for (int r = 0; r < 15; ++r) acc[r] = 0.f;
    const float* wrow = Wf2g + o * 64 + hh * 32;
    for (int c = 0; c < 32; ++c) {
      float wc = wrow[c];
      #pragma unroll
      for (int r = 0; r < 15; ++r) acc[r] += wc * x1ls[c * 15 + r];
    }
    #pragma unroll
    for (int r = 0; r < 15; ++r) pool[hh * 480 + o * 15 + r] = acc[r];
  }
  __syncthreads();
  {
    const float* A2 = pool + o * 15;
    const float* B2 = pool + 480 + o * 15;
    for (int t = 0; t < 10; ++t) {
      int e = hh * 10 + t; int m = e >> 2, kk = e & 3;
      int nb = idx2[m * 4 + kk];
      float p0 = A2[nb] - A2[m] + B2[m];
      float p1 = A2[5 + nb] - A2[5 + m] + B2[5 + m];
      float p2 = A2[10 + nb] - A2[10 + m] + B2[10 + m];
      float nrm = sqrtf(p0 * p0 + p1 * p1 + p2 * p2) + 1e-6f;
      accS += nrm; accQ += (double)nrm * (double)nrm;
    }
  }
  double oS = accS + __shfl_down(accS, 1, 64);
  double oQ = accQ + __shfl_down(accQ, 1, 64);
  if (hh == 0) {
    part[((size_t)s * 32 + o) * 2 + 0] = oS;
    part[((size_t)s * 32 + o) * 2 + 1] = oQ;
  }
}

// layer2 pass2 via A/B factorization + matrix maxpool + layer3 pass1 stats
__global__ __launch_bounds__(64, 4) void k_l2_pass2(const float* X1,
    const float* Wf2g, const float* Wd2g, const float* g2, const float* b2, const float* st2,
    const float* Wp2g, const float* Wf3g, float* X2, double* part)
{
  __shared__ float x1ls[480], dls[25], h2[96 * HS], x2ls[480];
  __shared__ float pool[32 * DVS];   // ABls[1920] (F/D mats), then dv matrix
  __shared__ float gls[32], bls[32], stls[64];
  __shared__ int idx2[20];
  int l = threadIdx.x;
  if (l < 32) { gls[l] = g2[l]; bls[l] = b2[l]; }
  if (l < 64) stls[l] = st2[l];
  int o = l >> 1, hh = l & 1;
  double accS = 0, accQ = 0;
  int s = blockIdx.x;
  __syncthreads();
  for (int r = l; r < 480; r += 64) x1ls[r] = X1[(size_t)s * 480 + r];
  __syncthreads();
  knn_compute(x1ls, 96, dls, idx2, l);
  // F pass (15 live regs), then D pass — numerically identical to fused version
  {
    float acc[15];
    #pragma unroll
    for (int r = 0; r < 15; ++r) acc[r] = 0.f;
    const float* wfrow = Wf2g + o * 64 + hh * 32;
    for (int c = 0; c < 32; ++c) {
      float wc = wfrow[c];
      #pragma unroll
      for (int r = 0; r < 15; ++r) acc[r] += wc * x1ls[c * 15 + r];
    }
    #pragma unroll
    for (int r = 0; r < 15; ++r) pool[hh * 480 + o * 15 + r] = acc[r];
  }
  {
    float acc[15];
    #pragma unroll
    for (int r = 0; r < 15; ++r) acc[r] = 0.f;
    const float* wdrow = Wd2g + o * 64 + hh * 32;
    for (int c = 0; c < 32; ++c) {
      float wc = wdrow[c];
      #pragma unroll
      for (int r = 0; r < 15; ++r) acc[r] += wc * x1ls[c * 15 + r];
    }
    #pragma unroll
    for (int r = 0; r < 15; ++r) pool[960 + hh * 480 + o * 15 + r] = acc[r];
  }
  __syncthreads();
  {
    float mean = stls[o * 2], rstd = stls[o * 2 + 1], gg = gls[o], bb = bls[o];
    const float* Af = pool + o * 15;
    const float* Bf = pool + 480 + o * 15;
    const float* Ad = pool + 960 + o * 15;
    const float* Bd = pool + 1440 + o * 15;
    for (int t = 0; t < 10; ++t) {
      int e = hh * 10 + t; int m = e >> 2, kk = e & 3;
      int nb = idx2[m * 4 + kk];
      float p[3], dd[3];
      #pragma unroll
      for (int j = 0; j < 3; ++j) {
        p[j]  = Af[j * 5 + nb] - Af[j * 5 + m] + Bf[j * 5 + m];
        dd[j] = Ad[j * 5 + nb] - Ad[j * 5 + m] + Bd[j * 5 + m];
      }
      float nrm = sqrtf(p[0] * p[0] + p[1] * p[1] + p[2] * p[2]) + 1e-6f;
      float outv[3];
      lrelu3(p, dd, nrm, mean, rstd, gg, bb, outv);
      h2[(o * 3 + 0) * HS + m * 4 + kk] = outv[0];
      h2[(o * 3 + 1) * HS + m * 4 + kk] = outv[1];
      h2[(o * 3 + 2) * HS + m * 4 + kk] = outv[2];
    }
  }
  __syncthreads();
  pool_dv_build(Wp2g, h2, pool, o, hh);   // overwrites dead ABls
  __syncthreads();
  for (int t = 0; t < 3; ++t) {
    int task = t * 64 + l;
    if (task < 160) {
      int oo = task & 31, m = task >> 5;
      float best = -3.4e38f; int bi = 0;
      for (int kk = 0; kk < 4; ++kk) {
        float acc = 0.f;
        for (int j = 0; j < 3; ++j)
          acc += h2[(oo * 3 + j) * HS + m * 4 + kk] * pool[oo * DVS + j * 20 + m * 4 + kk];
        if (acc > best) { best = acc; bi = kk; }
      }
      for (int j = 0; j < 3; ++j) {
        float v = h2[(oo * 3 + j) * HS + m * 4 + bi];
        x2ls[(oo * 3 + j) * 5 + m] = v;
        X2[(size_t)s * 480 + (oo * 3 + j) * 5 + m] = v;
      }
    }
  }
  __syncthreads();
  {
    int m0 = hh ? 3 : 0, mc = hh ? 2 : 3;
    for (int mi = 0; mi < mc; ++mi) {
      int m = m0 + mi;
      float p[3] = {0, 0, 0};
      for (int c = 0; c < 64; ++c) {
        float w = Wf3g[o * 64 + c];
        const float* src = (c < 32) ? (x1ls + c * 15) : (x2ls + (c - 32) * 15);
        p[0] += w * src[m]; p[1] += w * src[5 + m]; p[2] += w * src[10 + m];
      }
      float nrm = sqrtf(p[0] * p[0] + p[1] * p[1] + p[2] * p[2]) + 1e-6f;
      accS += nrm; accQ += (double)nrm * (double)nrm;
    }
  }
  double oS = accS + __shfl_down(accS, 1, 64);
  double oQ = accQ + __shfl_down(accQ, 1, 64);
  if (hh == 0) {
    part[((size_t)s * 32 + o) * 2 + 0] = oS;
    part[((size_t)s * 32 + o) * 2 + 1] = oQ;
  }
}

__global__ __launch_bounds__(64, 4) void k_l3_pass2(const float* X1, const float* X2,
    const float* Wf3g, const float* Wd3g, const float* g3, const float* b3, const float* st3,
    const float* Ws1fg, float* H3, double* part)
{
  __shared__ float x1ls[480], x2ls[480], h3ls[480], hm[96], d3ls[15];
  __shared__ float wd3[64];
  __shared__ float gls[32], bls[32], stls[64];
  int l = threadIdx.x;
  if (l < 64) wd3[l] = Wd3g[l];
  if (l < 32) { gls[l] = g3[l]; bls[l] = b3[l]; }
  if (l < 64) stls[l] = st3[l];
  int o = l >> 1, hh = l & 1;
  double accS = 0, accQ = 0;
  int s = blockIdx.x;
  __syncthreads();
  for (int r = l; r < 480; r += 64) { x1ls[r] = X1[(size_t)s * 480 + r]; x2ls[r] = X2[(size_t)s * 480 + r]; }
  __syncthreads();
  if (l < 15) {
    int j = l / 5, m = l % 5;
    float a = 0.f;
    for (int c = 0; c < 64; ++c) {
      const float* src = (c < 32) ? (x1ls + c * 15) : (x2ls + (c - 32) * 15);
      a += wd3[c] * src[j * 5 + m];
    }
    d3ls[l] = a;
  }
  __syncthreads();
  {
    int m0 = hh ? 3 : 0, mc = hh ? 2 : 3;
    float mean = stls[o * 2], rstd = stls[o * 2 + 1], gg = gls[o], bb = bls[o];
    const float* wrow = Wf3g + o * 64;
    for (int mi = 0; mi < mc; ++mi) {
      int m = m0 + mi;
      float p[3] = {0, 0, 0};
      for (int c = 0; c < 64; ++c) {
        float w = wrow[c];
        const float* src = (c < 32) ? (x1ls + c * 15) : (x2ls + (c - 32) * 15);
        p[0] += w * src[m]; p[1] += w * src[5 + m]; p[2] += w * src[10 + m];
      }
      float nrm = sqrtf(p[0] * p[0] + p[1] * p[1] + p[2] * p[2]) + 1e-6f;
      float dd[3] = {d3ls[m], d3ls[5 + m], d3ls[10 + m]};
      float outv[3];
      lrelu3(p, dd, nrm, mean, rstd, gg, bb, outv);
      h3ls[o * 15 + 0 + m] = outv[0];
      h3ls[o * 15 + 5 + m] = outv[1];
      h3ls[o * 15 + 10 + m] = outv[2];
      H3[(size_t)s * 480 + o * 15 + m] = outv[0];
      H3[(size_t)s * 480 + o * 15 + 5 + m] = outv[1];
      H3[(size_t)s * 480 + o * 15 + 10 + m] = outv[2];
    }
  }
  __syncthreads();
  for (int t = 0; t < 2; ++t) {
    int task = t * 64 + l;
    if (task < 96) {
      float a = h3ls[task * 5 + 0] + h3ls[task * 5 + 1] + h3ls[task * 5 + 2] + h3ls[task * 5 + 3] + h3ls[task * 5 + 4];
      hm[task] = a / 5.f;
    }
  }
  __syncthreads();
  {
    int m0 = hh ? 3 : 0, mc = hh ? 2 : 3;
    const float* wrow = Ws1fg + o * 64;
    for (int mi = 0; mi < mc; ++mi) {
      int m = m0 + mi;
      float p[3] = {0, 0, 0};
      for (int c = 0; c < 32; ++c) {
        float w = wrow[c];
        p[0] += w * h3ls[c * 15 + m]; p[1] += w * h3ls[c * 15 + 5 + m]; p[2] += w * h3ls[c * 15 + 10 + m];
      }
      for (int c = 0; c < 32; ++c) {
        float w = wrow[32 + c];
        p[0] += w * hm[c * 3 + 0]; p[1] += w * hm[c * 3 + 1]; p[2] += w * hm[c * 3 + 2];
      }
      float nrm = sqrtf(p[0] * p[0] + p[1] * p[1] + p[2] * p[2]) + 1e-6f;
      accS += nrm; accQ += (double)nrm * (double)nrm;
    }
  }
  double oS = accS + __shfl_down(accS, 1, 64);
  double oQ = accQ + __shfl_down(accQ, 1, 64);
  if (hh == 0) {
    part[((size_t)s * 32 + o) * 2 + 0] = oS;
    part[((size_t)s * 32 + o) * 2 + 1] = oQ;
  }
}

__global__ __launch_bounds__(64, 4) void k_s1_pass2(const float* H3,
    const float* Ws1fg, const float* Ws1dg, const float* gs1, const float* bs1, const float* st4,
    const float* Ws2fg, float* Z1, float* part5)
{
  __shared__ float h3ls[480], hm[96], z1ls[480];
  __shared__ float gls[32], bls[32], stls[64];
  int l = threadIdx.x;
  if (l < 32) { gls[l] = gs1[l]; bls[l] = bs1[l]; }
  if (l < 64) stls[l] = st4[l];
  int o = l >> 1, hh = l & 1;
  double accS = 0, accQ = 0;
  int s = blockIdx.x;
  __syncthreads();
  for (int r = l; r < 480; r += 64) h3ls[r] = H3[(size_t)s * 480 + r];
  __syncthreads();
  for (int t = 0; t < 2; ++t) {
    int task = t * 64 + l;
    if (task < 96) {
      float a = h3ls[task * 5 + 0] + h3ls[task * 5 + 1] + h3ls[task * 5 + 2] + h3ls[task * 5 + 3] + h3ls[task * 5 + 4];
      hm[task] = a / 5.f;
    }
  }
  __syncthreads();
  {
    int m0 = hh ? 3 : 0, mc = hh ? 2 : 3;
    float mean = stls[o * 2], rstd = stls[o * 2 + 1], gg = gls[o], bb = bls[o];
    const float* wfrow = Ws1fg + o * 64;
    const float* wdrow = Ws1dg + o * 64;
    for (int mi = 0; mi < mc; ++mi) {
      int m = m0 + mi;
      float p[3] = {0, 0, 0}, dd[3] = {0, 0, 0};
      for (int c = 0; c < 32; ++c) {
        float wA = wfrow[c], wB = wdrow[c];
        float v0 = h3ls[c * 15 + m], v1 = h3ls[c * 15 + 5 + m], v2 = h3ls[c * 15 + 10 + m];
        p[0] += wA * v0; p[1] += wA * v1; p[2] += wA * v2;
        dd[0] += wB * v0; dd[1] += wB * v1; dd[2] += wB * v2;
      }
      for (int c = 0; c < 32; ++c) {
        float wA = wfrow[32 + c], wB = wdrow[32 + c];
        float v0 = hm[c * 3 + 0], v1 = hm[c * 3 + 1], v2 = hm[c * 3 + 2];
        p[0] += wA * v0; p[1] += wA * v1; p[2] += wA * v2;
        dd[0] += wB * v0; dd[1] += wB * v1; dd[2] += wB * v2;
      }
      float nrm = sqrtf(p[0] * p[0] + p[1] * p[1] + p[2] * p[2]) + 1e-6f;
      float outv[3];
      lrelu3(p, dd, nrm, mean, rstd, gg, bb, outv);
      z1ls[o * 15 + m] = outv[0];
      z1ls[o * 15 + 5 + m] = outv[1];
      z1ls[o * 15 + 10 + m] = outv[2];
      Z1[(size_t)s * 480 + o * 15 + m] = outv[0];
      Z1[(size_t)s * 480 + o * 15 + 5 + m] = outv[1];
      Z1[(size_t)s * 480 + o * 15 + 10 + m] = outv[2];
    }
  }
  __syncthreads();
  if (l < 32) {
    int m0 = hh ? 3 : 0, mc = hh ? 2 : 3;
    const float* wrow = Ws2fg + o * 32;
    for (int mi = 0; mi < mc; ++mi) {
      int m = m0 + mi;
      float p[3] = {0, 0, 0};
      for (int c = 0; c < 32; ++c) {
        float w = wrow[c];
        p[0] += w * z1ls[c * 15 + m]; p[1] += w * z1ls[c * 15 + 5 + m]; p[2] += w * z1ls[c * 15 + 10 + m];
      }
      float nrm = sqrtf(p[0] * p[0] + p[1] * p[1] + p[2] * p[2]) + 1e-6f;
      accS += nrm; accQ += (double)nrm * (double)nrm;
    }
  }
  double oS = accS + __shfl_down(accS, 1, 64);
  double oQ = accQ + __shfl_down(accQ, 1, 64);
  if (hh == 0 && l < 32) {
    part5[((size_t)s * 16 + o) * 2 + 0] = (float)oS;
    part5[((size_t)s * 16 + o) * 2 + 1] = (float)oQ;
  }
}

__global__ __launch_bounds__(64, 4) void k_final(const float* Z1, const float* H3,
    const float* X1, const float* X2,
    const float* Ws2fg, const float* Ws2dg, const float* gs2, const float* bs2, const float* st5,
    const float* Wsling, const float* Wh1g, const float* bh1g, const float* Wh2g, const float* Wp3g,
    const float* scn, const float* rotn,
    float* out_hs, float* out_ks, float* ENT)
{
  __shared__ float z1ls[480], h3ls[480], x1ls[480], x2ls[480], hm[96];
  __shared__ float z2ls[240], z0ls[45], xmaxls[192];
  __shared__ float phsp[320], xmp[64];
  __shared__ float pooled[96], phsls[5];
  __shared__ double D3ls[32 * 17], pkd[9];   // dv matrix for Wp3 pool (double, pad 17)
  __shared__ float mat[25], mat2[25], scls[5], ssls[5];
  __shared__ int ordls[5];
  __shared__ float gls[16], bls[16], stls[32];
  int l = threadIdx.x;
  if (l < 16) { gls[l] = gs2[l]; bls[l] = bs2[l]; }
  if (l < 32) stls[l] = st5[l];
  float bh1v = bh1g[0];
  int o = l >> 1, hh = l & 1;
  int s = blockIdx.x;
  __syncthreads();
  for (int r = l; r < 480; r += 64) {
    z1ls[r] = Z1[(size_t)s * 480 + r];
    h3ls[r] = H3[(size_t)s * 480 + r];
    x1ls[r] = X1[(size_t)s * 480 + r];
    x2ls[r] = X2[(size_t)s * 480 + r];
  }
  __syncthreads();
  if (l < 32) {
    int m0 = hh ? 3 : 0, mc = hh ? 2 : 3;
    float mean = stls[o * 2], rstd = stls[o * 2 + 1], gg = gls[o], bb = bls[o];
    const float* wfrow = Ws2fg + o * 32;
    const float* wdrow = Ws2dg + o * 32;
    for (int mi = 0; mi < mc; ++mi) {
      int m = m0 + mi;
      float p[3] = {0, 0, 0}, dd[3] = {0, 0, 0};
      for (int c = 0; c < 32; ++c) {
        float wA = wfrow[c], wB = wdrow[c];
        float v0 = z1ls[c * 15 + m], v1 = z1ls[c * 15 + 5 + m], v2 = z1ls[c * 15 + 10 + m];
        p[0] += wA * v0; p[1] += wA * v1; p[2] += wA * v2;
        dd[0] += wB * v0; dd[1] += wB * v1; dd[2] += wB * v2;
      }
      float nrm = sqrtf(p[0] * p[0] + p[1] * p[1] + p[2] * p[2]) + 1e-6f;
      float outv[3];
      lrelu3(p, dd, nrm, mean, rstd, gg, bb, outv);
      z2ls[o * 15 + m] = outv[0];
      z2ls[o * 15 + 5 + m] = outv[1];
      z2ls[o * 15 + 10 + m] = outv[2];
    }
  }
  for (int t = 0; t < 2; ++t) {
    int task = t * 64 + l;
    if (task < 96) {
      float a = h3ls[task * 5 + 0] + h3ls[task * 5 + 1] + h3ls[task * 5 + 2] + h3ls[task * 5 + 3] + h3ls[task * 5 + 4];
      hm[task] = a / 5.f;
    }
  }
  __syncthreads();
  if (l < 45) {
    int j = l / 15, kk = (l / 5) % 3, m = l % 5;
    float a = 0.f;
    for (int c = 0; c < 16; ++c) a += Wsling[j * 16 + c] * z2ls[c * 15 + kk * 5 + m];
    z0ls[l] = a;
  }
  __syncthreads();
  for (int t = 0; t < 3; ++t) {
    int r = t * 64 + l;
    if (r < 192) {
      int i = r / 3, kk = r % 3;
      float vmax = -3.4e38f;
      for (int m = 0; m < 5; ++m) {
        float v = 0.f;
        #pragma unroll
        for (int j = 0; j < 3; ++j) {
          float hv = (i < 32) ? h3ls[i * 15 + j * 5 + m] : hm[(i - 32) * 3 + j];
          v += hv * z0ls[(j * 3 + kk) * 5 + m];
        }
        vmax = fmaxf(vmax, v);
      }
      xmaxls[r] = vmax;
    }
  }
  __syncthreads();
  {
    float xmacc = 0.f;
    float pacc[5] = {0, 0, 0, 0, 0};
    for (int rr = l; rr < 192; rr += 64) {
      xmacc += Wh1g[rr] * xmaxls[rr];
      int i = rr / 3, kk = rr % 3;
      float w = Wh1g[192 + rr];
      for (int m = 0; m < 5; ++m) {
        float v = 0.f;
        #pragma unroll
        for (int j = 0; j < 3; ++j) {
          float xv = (i < 32) ? x1ls[i * 15 + j * 5 + m] : x2ls[(i - 32) * 15 + j * 5 + m];
          v += xv * z0ls[(j * 3 + kk) * 5 + m];
        }
        pacc[m] += w * v;
      }
    }
    xmp[l] = xmacc;
    #pragma unroll
    for (int m = 0; m < 5; ++m) phsp[m * 64 + l] = pacc[m];
  }
  __syncthreads();
  if (l < 5) {
    float xs = 0.f;
    for (int k2 = 0; k2 < 64; ++k2) xs += xmp[k2];
    float a = 0.f;
    for (int k2 = 0; k2 < 64; ++k2) a += phsp[l * 64 + k2];
    phsls[l] = xs + a + bh1v;
  }
  // D3 matrix: dv[cc][j*5+m] = sum_c2 wp3[cc][c2]*x1[c2][j][m], double, c2 ascending.
  // lane (o=cc, hh): hh=0 -> m 0..2, hh=1 -> m 2..4 (m=2 written twice, identical value)
  {
    const float* wrow = Wp3g + o * 32;
    int m0 = hh ? 2 : 0;
    for (int j = 0; j < 3; ++j) {
      double acc[3] = {0.0, 0.0, 0.0};
      for (int c2 = 0; c2 < 32; ++c2) {
        double w = (double)wrow[c2];
        #pragma unroll
        for (int mi = 0; mi < 3; ++mi)
          acc[mi] += w * (double)x1ls[c2 * 15 + j * 5 + m0 + mi];
      }
      #pragma unroll
      for (int mi = 0; mi < 3; ++mi) D3ls[o * 17 + j * 5 + m0 + mi] = acc[mi];
    }
  }
  __syncthreads();
  if (l < 32) {
    double best = -1e300; int bi = 0;
    for (int m = 0; m < 5; ++m) {
      double v = 0.0;
      for (int j = 0; j < 3; ++j)
        v += (double)x1ls[l * 15 + j * 5 + m] * D3ls[l * 17 + j * 5 + m];
      if (v > best) { best = v; bi = m; }
    }
    pooled[l * 3 + 0] = x1ls[l * 15 + bi];
    pooled[l * 3 + 1] = x1ls[l * 15 + 5 + bi];
    pooled[l * 3 + 2] = x1ls[l * 15 + 10 + bi];
  }
  __syncthreads();
  if (l < 9) {
    int o2 = l / 3, i = l % 3;
    double a = 0.0;
    for (int c = 0; c < 32; ++c) a += (double)Wh2g[o2 * 32 + c] * (double)pooled[c * 3 + i];
    pkd[i * 3 + o2] = a;
  }
  if (l < 5) scls[l] = phsls[l] + scn[(size_t)s * 5 + l];
  __syncthreads();
  if (l < 5) {
    float nr = sqrtf(scls[0] * scls[0] + scls[1] * scls[1] + scls[2] * scls[2] + scls[3] * scls[3] + scls[4] * scls[4]);
    float v = scls[l] / fmaxf(nr, 1e-12f);
    __syncthreads();
    scls[l] = v;
  } else { __syncthreads(); }
  __syncthreads();
  if (l == 0) {
    unsigned chosen = 0u;
    for (int r = 0; r < 5; ++r) {
      float best = -3.4e38f; int bi = 0;
      for (int n = 0; n < 5; ++n) {
        if ((chosen >> n) & 1u) continue;
        if (scls[n] > best) { best = scls[n]; bi = n; }
      }
      ordls[r] = bi; ssls[r] = best; chosen |= (1u << bi);
    }
  }
  __syncthreads();
  float lp = 0.f;
  if (l < 25) {
    int i = l / 5, j = l % 5;
    lp = -fabsf(scls[i] - ssls[j]) / 0.01f;
  }
  for (int itn = 0; itn < 20; ++itn) {
    if (l < 25) mat[l] = lp;
    __syncthreads();
    if (l < 25) {
      int i = l / 5;
      float m0 = mat[i * 5], m1 = mat[i * 5 + 1], m2 = mat[i * 5 + 2], m3 = mat[i * 5 + 3], m4 = mat[i * 5 + 4];
      float mx = fmaxf(fmaxf(fmaxf(m0, m1), fmaxf(m2, m3)), m4);
      float ssum = expf(m0 - mx) + expf(m1 - mx) + expf(m2 - mx) + expf(m3 - mx) + expf(m4 - mx);
      lp -= (mx + logf(ssum));
    }
    __syncthreads();
    if (l < 25) mat[l] = lp;
    __syncthreads();
    if (l < 25) {
      int j = l % 5;
      float m0 = mat[j], m1 = mat[5 + j], m2 = mat[10 + j], m3 = mat[15 + j], m4 = mat[20 + j];
      float mx = fmaxf(fmaxf(fmaxf(m0, m1), fmaxf(m2, m3)), m4);
      float ssum = expf(m0 - mx) + expf(m1 - mx) + expf(m2 - mx) + expf(m3 - mx) + expf(m4 - mx);
      lp -= (mx + logf(ssum));
    }
    __syncthreads();
  }
  float soft = 0.f;
  if (l < 25) {
    int i = l / 5, j = l % 5;
    soft = expf(lp);
    float hard = (ordls[j] == i) ? 1.f : 0.f;
    out_hs[(size_t)s * 25 + l] = (hard - soft) + soft;
    mat[l] = fmaxf(soft, 1e-12f);
  }
  __syncthreads();
  if (l < 25) {
    int i = l / 5, j = l % 5;
    float scl = mat[l];
    float colsum = mat[j] + mat[5 + j] + mat[10 + j] + mat[15 + j] + mat[20 + j];
    float rowsum = mat[i * 5] + mat[i * 5 + 1] + mat[i * 5 + 2] + mat[i * 5 + 3] + mat[i * 5 + 4];
    float pc = scl / fmaxf(colsum, 1e-12f);
    float pr = scl / fmaxf(rowsum, 1e-12f);
    float t2 = -pc * fmaxf(logf(pc), -100.f);
    float t3 = -pr * fmaxf(logf(pr), -100.f);
    mat2[l] = t2 + t3;
  }
  __syncthreads();
  if (l == 0) {
    float a = 0.f;
    for (int k2 = 0; k2 < 25; ++k2) a += mat2[k2];
    ENT[s] = a;
    double M[9];
    #pragma unroll
    for (int r = 0; r < 9; ++r) M[r] = pkd[r] + (double)rotn[(size_t)s * 9 + r];
    double a0 = M[0], a1 = M[3], a2 = M[6];
    double n0 = sqrt(a0 * a0 + a1 * a1 + a2 * a2) + 1e-12;
    double e10 = a0 / n0, e11 = a1 / n0, e12 = a2 / n0;
    double b0 = M[1], b1 = M[4], b2 = M[7];
    double t1 = e10 * b0 + e11 * b1 + e12 * b2;
    double v20 = b0 - t1 * e10, v21 = b1 - t1 * e11, v22 = b2 - t1 * e12;
    double n2 = sqrt(v20 * v20 + v21 * v21 + v22 * v22) + 1e-12;
    double e20 = v20 / n2, e21 = v21 / n2, e22 = v22 / n2;
    double c0 = M[2], c1 = M[5], c2 = M[8];
    double ta = e10 * c0 + e11 * c1 + e12 * c2;
    double tb = e20 * c0 + e21 * c1 + e22 * c2;
    double v30 = c0 - ta * e10 - tb * e20, v31 = c1 - ta * e11 - tb * e21, v32 = c2 - ta * e12 - tb * e22;
    double n3 = sqrt(v30 * v30 + v31 * v31 + v32 * v32) + 1e-12;
    double e30 = v30 / n3, e31 = v31 / n3, e32 = v32 / n3;
    float* dst = out_ks + (size_t)s * 9;
    dst[0] = (float)e10; dst[1] = (float)e20; dst[2] = (float)e30;
    dst[3] = (float)e11; dst[4] = (float)e21; dst[5] = (float)e31;
    dst[6] = (float)e12; dst[7] = (float)e22; dst[8] = (float)e32;
  }
}

__global__ __launch_bounds__(256) void k_ent_red(const float* ENT, float* outp)
{
  __shared__ double red[256];
  int t = threadIdx.x;
  double a = 0;
  for (int i = t; i < 8192; i += 256) a += (double)ENT[i];
  red[t] = a;
  __syncthreads();
  if (t == 0) {
    double sum = 0;
    for (int k = 0; k < 256; ++k) sum += red[k];
    outp[0] = (float)(sum / 40960.0);
  }
}

// ---------------------------------------------------------------- launch

extern "C" void kernel_launch(void* const* d_in, const int* in_sizes, int n_in,
                              void* d_out, int out_size, void* d_ws, size_t ws_size,
                              hipStream_t stream)
{
  (void)in_sizes; (void)n_in; (void)out_size;
  const float* nf    = (const float*)d_in[0];
  const float* noise = (const float*)d_in[1];
  const float* scn   = (const float*)d_in[2];
  const float* rotn  = (const float*)d_in[3];
  const float* Wf1 = (const float*)d_in[4],  *Wd1 = (const float*)d_in[5];
  const float* g1  = (const float*)d_in[6],  *b1  = (const float*)d_in[7];
  const float* Wf2 = (const float*)d_in[8],  *Wd2 = (const float*)d_in[9];
  const float* g2  = (const float*)d_in[10], *b2  = (const float*)d_in[11];
  const float* Wf3 = (const float*)d_in[12], *Wd3 = (const float*)d_in[13];
  const float* g3  = (const float*)d_in[14], *b3  = (const float*)d_in[15];
  const float* Wp1 = (const float*)d_in[16], *Wp2 = (const float*)d_in[17], *Wp3 = (const float*)d_in[18];
  const float* Ws1f = (const float*)d_in[19], *Ws1d = (const float*)d_in[20];
  const float* gs1  = (const float*)d_in[21], *bs1  = (const float*)d_in[22];
  const float* Ws2f = (const float*)d_in[23], *Ws2d = (const float*)d_in[24];
  const float* gs2  = (const float*)d_in[25], *bs2  = (const float*)d_in[26];
  const float* Wslin = (const float*)d_in[27];
  const float* Wh1   = (const float*)d_in[28];
  const float* bh1   = (const float*)d_in[29];
  const float* Wh2   = (const float*)d_in[30];

  // workspace layout (total 63,997,184 B, unchanged):
  //   X1, X2, H3, Z1 : 4 x 15,728,640 B
  //   ENT            : 32,768 B   (doubles as RED1 scratch for the reduces)
  //   ST             : 1,280 B
  //   legacy slot    : 1,048,576 B (PART5 float pairs)
  // PART_main (4 MB doubles) aliases the head of Z1 (dead until k_s1_pass2).
  const size_t SZ = (size_t)8192 * 480;
  if (ws_size < 63997184ull) return;
  float* ws  = (float*)d_ws;
  float* X1  = ws;
  float* X2  = X1 + SZ;
  float* H3  = X2 + SZ;
  float* Z1  = H3 + SZ;
  float* ENT = Z1 + SZ;
  float* ST  = ENT + 8192;
  float* PART5 = ST + 320;
  double* PARTm = (double*)Z1;
  double* RED1  = (double*)ENT;
  float* st1 = ST, *st2 = ST + 64, *st3 = ST + 128, *st4 = ST + 192, *st5 = ST + 256;

  float* out_hs = (float*)d_out;
  float* out_ks = out_hs + 204800;
  float* out_sc = out_hs + 278528;

  dim3 grid(NSAMP), blk(64);
  k_l1_pass1<<<grid, blk, 0, stream>>>(nf, noise, Wf1, PARTm);
  k_red1<<<64, 64, 0, stream>>>(PARTm, RED1, 32);
  k_red2<<<1, 64, 0, stream>>>(RED1, st1, 32, 163840.f);
  k_l1_pass2<<<grid, blk, 0, stream>>>(nf, noise, Wf1, Wd1, g1, b1, st1, Wp1, Wf2, X1, PARTm);
  k_red1<<<64, 64, 0, stream>>>(PARTm, RED1, 32);
  k_red2<<<1, 64, 0, stream>>>(RED1, st2, 32, 163840.f);
  k_l2_pass2<<<grid, blk, 0, stream>>>(X1, Wf2, Wd2, g2, b2, st2, Wp2, Wf3, X2, PARTm);
  k_red1<<<64, 64, 0, stream>>>(PARTm, RED1, 32);
  k_red2<<<1, 64, 0, stream>>>(RED1, st3, 32, 40960.f);
  k_l3_pass2<<<grid, blk, 0, stream>>>(X1, X2, Wf3, Wd3, g3, b3, st3, Ws1f, H3, PARTm);
  k_red1<<<64, 64, 0, stream>>>(PARTm, RED1, 32);
  k_red2<<<1, 64, 0, stream>>>(RED1, st4, 32, 40960.f);
  k_s1_pass2<<<grid, blk, 0, stream>>>(H3, Ws1f, Ws1d, gs1, bs1, st4, Ws2f, Z1, PART5);
  k_red1f<<<64, 64, 0, stream>>>(PART5, RED1, 16);
  k_red2<<<1, 64, 0, stream>>>(RED1, st5, 16, 40960.f);
  k_final<<<grid, blk, 0, stream>>>(Z1, H3, X1, X2, Ws2f, Ws2d, gs2, bs2, st5,
                                    Wslin, Wh1, bh1, Wh2, Wp3, scn, rotn,
                                    out_hs, out_ks, ENT);
  k_ent_red<<<1, 256, 0, stream>>>(ENT, out_sc);
}

// Round 10
// 664.598 us; speedup vs baseline: 1.4245x; 1.4245x over previous
//
#include <hip/hip_runtime.h>
#include <math.h>

#define NSAMP 8192   // one block per sample

// LDS padding strides
#define WS4  5    // [32][4] weights
#define HS   21   // h1/h2 row stride (logical 20)

// ---------------------------------------------------------------- helpers

__device__ __forceinline__ void knn_compute(const float* xls, int C3, float* dls, int* idxls, int l)
{
  if (l < 25) {
    int m = l / 5, n = l % 5;
    float acc = 0.f;
    for (int r = 0; r < C3; ++r) acc += xls[r * 5 + m] * xls[r * 5 + n];
    dls[l] = acc;  // inner
  }
  __syncthreads();
  float dm = 0.f, dn = 0.f, inn = 0.f;
  if (l < 25) { int m = l / 5, n = l % 5; dm = dls[m * 5 + m]; dn = dls[n * 5 + n]; inn = dls[l]; }
  __syncthreads();
  if (l < 25) dls[l] = 2.f * inn - dm - dn;
  __syncthreads();
  if (l < 5) {
    int m = l; unsigned chosen = 0u;
    for (int kk = 0; kk < 4; ++kk) {
      float best = -3.4e38f; int bi = 0;
      for (int n = 0; n < 5; ++n) {
        if ((chosen >> n) & 1u) continue;
        float v = dls[m * 5 + n];
        if (v > best) { best = v; bi = n; }
      }
      idxls[m * 4 + kk] = bi;
      chosen |= (1u << bi);
    }
  }
  __syncthreads();
}

template<bool WD>
__device__ __forceinline__ void feat_pd2(const float* xls, const int* idxls,
    const float* Wf, const float* Wd, int o, int m, int kk, float* p, float* d)
{
  const int nb = idxls[m * 4 + kk];
  const float* wf = Wf + o * WS4;
  const float* wd = WD ? (Wd + o * WS4) : wf;
  for (int c = 0; c < 2; ++c) {
    float wfc = wf[c];
    float wdc = WD ? wd[c] : 0.f;
    #pragma unroll
    for (int j = 0; j < 3; ++j) {
      float v = xls[c * 15 + j * 5 + nb] - xls[c * 15 + j * 5 + m];
      p[j] += wfc * v;
      if (WD) d[j] += wdc * v;
    }
  }
  for (int c = 0; c < 2; ++c) {
    float wfc = wf[2 + c];
    float wdc = WD ? wd[2 + c] : 0.f;
    #pragma unroll
    for (int j = 0; j < 3; ++j) {
      float v = xls[c * 15 + j * 5 + m];
      p[j] += wfc * v;
      if (WD) d[j] += wdc * v;
    }
  }
}

__device__ __forceinline__ void lrelu3(const float* p, const float* d, float nrm,
    float mean, float rstd, float g, float b, float* out)
{
  float nbn = g * (nrm - mean) * rstd + b;
  float s = nbn / nrm;
  float pb0 = p[0] * s, pb1 = p[1] * s, pb2 = p[2] * s;
  float dot = pb0 * d[0] + pb1 * d[1] + pb2 * d[2];
  if (dot >= 0.f) { out[0] = pb0; out[1] = pb1; out[2] = pb2; }
  else {
    float dsq = d[0] * d[0] + d[1] * d[1] + d[2] * d[2];
    float f = 0.8f * (dot / (dsq + 1e-6f));
    out[0] = pb0 - f * d[0]; out[1] = pb1 - f * d[1]; out[2] = pb2 - f * d[2];
  }
}

__device__ __forceinline__ void load_x_sample(const float* nf, const float* noise, int s, int l, float* xls)
{
  if (l < 30) {
    int c = l / 15, j = (l / 5) % 3, m = l % 5, b = s >> 6;
    xls[l] = nf[((b * 5 + m) * 3 + j) * 2 + c] + noise[(((size_t)s * 5 + m) * 3 + j) * 2 + c];
  }
}

// maxpool with 12 independent accumulators (ILP) — bit-identical order:
// dv[kk][j] sums c ascending; final dot sums j ascending; first-wins argmax.
__device__ __forceinline__ void maxpool_task(const float* Wg, const float* H,
    int oo, int m, int* bi_out)
{
  const float* wrow = Wg + oo * 32;
  float acc[4][3];
  #pragma unroll
  for (int kk = 0; kk < 4; ++kk)
    #pragma unroll
    for (int j = 0; j < 3; ++j) acc[kk][j] = 0.f;
  for (int c = 0; c < 32; ++c) {
    float w = wrow[c];
    #pragma unroll
    for (int j = 0; j < 3; ++j) {
      const float* hrow = H + (c * 3 + j) * HS + m * 4;
      #pragma unroll
      for (int kk = 0; kk < 4; ++kk) acc[kk][j] += w * hrow[kk];
    }
  }
  float best = -3.4e38f; int bi = 0;
  #pragma unroll
  for (int kk = 0; kk < 4; ++kk) {
    float a2 = 0.f;
    #pragma unroll
    for (int j = 0; j < 3; ++j) a2 += H[(oo * 3 + j) * HS + m * 4 + kk] * acc[kk][j];
    if (a2 > best) { best = a2; bi = kk; }
  }
  *bi_out = bi;
}

// ---------------------------------------------------------------- kernels

__global__ __launch_bounds__(64) void k_l1_pass1(const float* nf, const float* noise,
    const float* Wf1, double* part)
{
  __shared__ float xls[30], dls[25], wf[32 * WS4];
  __shared__ int idxls[20];
  int l = threadIdx.x;
  for (int r = l; r < 128; r += 64) wf[(r >> 2) * WS4 + (r & 3)] = Wf1[r];
  int o = l >> 1, hh = l & 1;
  double accS = 0, accQ = 0;
  int s = blockIdx.x;
  __syncthreads();
  load_x_sample(nf, noise, s, l, xls);
  __syncthreads();
  knn_compute(xls, 6, dls, idxls, l);
  for (int t = 0; t < 10; ++t) {
    int e = hh * 10 + t; int m = e >> 2, kk = e & 3;
    float p[3] = {0, 0, 0}, dum[3];
    feat_pd2<false>(xls, idxls, wf, wf, o, m, kk, p, dum);
    float nrm = sqrtf(p[0] * p[0] + p[1] * p[1] + p[2] * p[2]) + 1e-6f;
    accS += nrm; accQ += (double)nrm * (double)nrm;
  }
  double oS = accS + __shfl_down(accS, 1, 64);
  double oQ = accQ + __shfl_down(accQ, 1, 64);
  if (hh == 0) {
    part[((size_t)s * 32 + o) * 2 + 0] = oS;
    part[((size_t)s * 32 + o) * 2 + 1] = oQ;
  }
}

// two-stage deterministic reduce
__global__ __launch_bounds__(64) void k_red1(const double* part, double* red1, int C)
{
  int p = threadIdx.x, b = blockIdx.x;
  double acc = 0;
  if (p < 2 * C) {
    int o = p >> 1, q = p & 1;
    for (int g = b * 128; g < (b + 1) * 128; ++g)
      acc += part[((size_t)g * C + o) * 2 + q];
  }
  red1[b * 64 + p] = acc;
}

__global__ __launch_bounds__(64) void k_red1f(const float* part, double* red1, int C)
{
  int p = threadIdx.x, b = blockIdx.x;
  double acc = 0;
  if (p < 2 * C) {
    int o = p >> 1, q = p & 1;
    for (int g = b * 128; g < (b + 1) * 128; ++g)
      acc += (double)part[((size_t)g * C + o) * 2 + q];
  }
  red1[b * 64 + p] = acc;
}

__global__ __launch_bounds__(64) void k_red2(const double* red1, float* stats, int C, float count)
{
  __shared__ double tot[64];
  int p = threadIdx.x;
  double a = 0;
  if (p < 2 * C) for (int b = 0; b < 64; ++b) a += red1[b * 64 + p];
  tot[p] = a;
  __syncthreads();
  if (p < C) {
    double sum = tot[p * 2 + 0], ssq = tot[p * 2 + 1];
    double mean = sum / (double)count;
    double var = ssq / (double)count - mean * mean;
    stats[p * 2 + 0] = (float)mean;
    stats[p * 2 + 1] = (float)(1.0 / sqrt(var + 1e-5));
  }
}

// layer1 pass2 (h1, maxpool->x1) + layer2 pass1 stats via A/B factorization
__global__ __launch_bounds__(64) void k_l1_pass2(const float* nf, const float* noise,
    const float* Wf1g, const float* Wd1g, const float* g1, const float* b1, const float* st1,
    const float* Wp1g, const float* Wf2g, float* X1, double* part)
{
  __shared__ float xls[30], dls[25], h1[96 * HS], x1ls[480];
  __shared__ float wf1[32 * WS4], wd1[32 * WS4];
  __shared__ float AB2[960];
  __shared__ float gls[32], bls[32], stls[64];
  __shared__ int idxls[20], idx2[20];
  int l = threadIdx.x;
  for (int r = l; r < 128; r += 64) { int q = (r >> 2) * WS4 + (r & 3); wf1[q] = Wf1g[r]; wd1[q] = Wd1g[r]; }
  if (l < 32) { gls[l] = g1[l]; bls[l] = b1[l]; }
  if (l < 64) stls[l] = st1[l];
  int o = l >> 1, hh = l & 1;
  double accS = 0, accQ = 0;
  int s = blockIdx.x;
  __syncthreads();
  load_x_sample(nf, noise, s, l, xls);
  __syncthreads();
  knn_compute(xls, 6, dls, idxls, l);
  {
    float mean = stls[o * 2], rstd = stls[o * 2 + 1], gg = gls[o], bb = bls[o];
    for (int t = 0; t < 10; ++t) {
      int e = hh * 10 + t; int m = e >> 2, kk = e & 3;
      float p[3] = {0, 0, 0}, dd[3] = {0, 0, 0};
      feat_pd2<true>(xls, idxls, wf1, wd1, o, m, kk, p, dd);
      float nrm = sqrtf(p[0] * p[0] + p[1] * p[1] + p[2] * p[2]) + 1e-6f;
      float outv[3];
      lrelu3(p, dd, nrm, mean, rstd, gg, bb, outv);
      h1[(o * 3 + 0) * HS + m * 4 + kk] = outv[0];
      h1[(o * 3 + 1) * HS + m * 4 + kk] = outv[1];
      h1[(o * 3 + 2) * HS + m * 4 + kk] = outv[2];
    }
  }
  __syncthreads();
  for (int t = 0; t < 3; ++t) {
    int task = t * 64 + l;
    if (task < 160) {
      int oo = task & 31, m = task >> 5;
      int bi;
      maxpool_task(Wp1g, h1, oo, m, &bi);
      for (int j = 0; j < 3; ++j) {
        float v = h1[(oo * 3 + j) * HS + m * 4 + bi];
        x1ls[(oo * 3 + j) * 5 + m] = v;
        X1[(size_t)s * 480 + (oo * 3 + j) * 5 + m] = v;
      }
    }
  }
  __syncthreads();
  knn_compute(x1ls, 96, dls, idx2, l);
  {
    float acc[15];
    #pragma unroll
    for (int r = 0; r < 15; ++r) acc[r] = 0.f;
    const float* wrow = Wf2g + o * 64 + hh * 32;
    for (int c = 0; c < 32; ++c) {
      float wc = wrow[c];
      #pragma unroll
      for (int r = 0; r < 15; ++r) acc[r] += wc * x1ls[c * 15 + r];
    }
    #pragma unroll
    for (int r = 0; r < 15; ++r) AB2[hh * 480 + o * 15 + r] = acc[r];
  }
  __syncthreads();
  {
    const float* A2 = AB2 + o * 15;
    const float* B2 = AB2 + 480 + o * 15;
    for (int t = 0; t < 10; ++t) {
      int e = hh * 10 + t; int m = e >> 2, kk = e & 3;
      int nb = idx2[m * 4 + kk];
      float p0 = A2[nb] - A2[m] + B2[m];
      float p1 = A2[5 + nb] - A2[5 + m] + B2[5 + m];
      float p2 = A2[10 + nb] - A2[10 + m] + B2[10 + m];
      float nrm = sqrtf(p0 * p0 + p1 * p1 + p2 * p2) + 1e-6f;
      accS += nrm; accQ += (double)nrm * (double)nrm;
    }
  }
  double oS = accS + __shfl_down(accS, 1, 64);
  double oQ = accQ + __shfl_down(accQ, 1, 64);
  if (hh == 0) {
    part[((size_t)s * 32 + o) * 2 + 0] = oS;
    part[((size_t)s * 32 + o) * 2 + 1] = oQ;
  }
}

// layer2 pass2 via A/B factorization + maxpool + layer3 pass1 stats
__global__ __launch_bounds__(64) void k_l2_pass2(const float* X1,
    const float* Wf2g, const float* Wd2g, const float* g2, const float* b2, const float* st2,
    const float* Wp2g, const float* Wf3g, float* X2, double* part)
{
  __shared__ float x1ls[480], dls[25], h2[96 * HS], x2ls[480];
  __shared__ float ABls[1920];
  __shared__ float gls[32], bls[32], stls[64];
  __shared__ int idx2[20];
  int l = threadIdx.x;
  if (l < 32) { gls[l] = g2[l]; bls[l] = b2[l]; }
  if (l < 64) stls[l] = st2[l];
  int o = l >> 1, hh = l & 1;
  double accS = 0, accQ = 0;
  int s = blockIdx.x;
  __syncthreads();
  for (int r = l; r < 480; r += 64) x1ls[r] = X1[(size_t)s * 480 + r];
  __syncthreads();
  knn_compute(x1ls, 96, dls, idx2, l);
  {
    float accF[15], accD[15];
    #pragma unroll
    for (int r = 0; r < 15; ++r) { accF[r] = 0.f; accD[r] = 0.f; }
    const float* wfrow = Wf2g + o * 64 + hh * 32;
    const float* wdrow = Wd2g + o * 64 + hh * 32;
    for (int c = 0; c < 32; ++c) {
      float wfc = wfrow[c], wdc = wdrow[c];
      #pragma unroll
      for (int r = 0; r < 15; ++r) {
        float xv = x1ls[c * 15 + r];
        accF[r] += wfc * xv;
        accD[r] += wdc * xv;
      }
    }
    #pragma unroll
    for (int r = 0; r < 15; ++r) {
      ABls[hh * 480 + o * 15 + r] = accF[r];
      ABls[960 + hh * 480 + o * 15 + r] = accD[r];
    }
  }
  __syncthreads();
  {
    float mean = stls[o * 2], rstd = stls[o * 2 + 1], gg = gls[o], bb = bls[o];
    const float* Af = ABls + o * 15;
    const float* Bf = ABls + 480 + o * 15;
    const float* Ad = ABls + 960 + o * 15;
    const float* Bd = ABls + 1440 + o * 15;
    for (int t = 0; t < 10; ++t) {
      int e = hh * 10 + t; int m = e >> 2, kk = e & 3;
      int nb = idx2[m * 4 + kk];
      float p[3], dd[3];
      #pragma unroll
      for (int j = 0; j < 3; ++j) {
        p[j]  = Af[j * 5 + nb] - Af[j * 5 + m] + Bf[j * 5 + m];
        dd[j] = Ad[j * 5 + nb] - Ad[j * 5 + m] + Bd[j * 5 + m];
      }
      float nrm = sqrtf(p[0] * p[0] + p[1] * p[1] + p[2] * p[2]) + 1e-6f;
      float outv[3];
      lrelu3(p, dd, nrm, mean, rstd, gg, bb, outv);
      h2[(o * 3 + 0) * HS + m * 4 + kk] = outv[0];
      h2[(o * 3 + 1) * HS + m * 4 + kk] = outv[1];
      h2[(o * 3 + 2) * HS + m * 4 + kk] = outv[2];
    }
  }
  __syncthreads();
  for (int t = 0; t < 3; ++t) {
    int task = t * 64 + l;
    if (task < 160) {
      int oo = task & 31, m = task >> 5;
      int bi;
      maxpool_task(Wp2g, h2, oo, m, &bi);
      for (int j = 0; j < 3; ++j) {
        float v = h2[(oo * 3 + j) * HS + m * 4 + bi];
        x2ls[(oo * 3 + j) * 5 + m] = v;
        X2[(size_t)s * 480 + (oo * 3 + j) * 5 + m] = v;
      }
    }
  }
  __syncthreads();
  {
    int m0 = hh ? 3 : 0, mc = hh ? 2 : 3;
    for (int mi = 0; mi < mc; ++mi) {
      int m = m0 + mi;
      float p[3] = {0, 0, 0};
      for (int c = 0; c < 64; ++c) {
        float w = Wf3g[o * 64 + c];
        const float* src = (c < 32) ? (x1ls + c * 15) : (x2ls + (c - 32) * 15);
        p[0] += w * src[m]; p[1] += w * src[5 + m]; p[2] += w * src[10 + m];
      }
      float nrm = sqrtf(p[0] * p[0] + p[1] * p[1] + p[2] * p[2]) + 1e-6f;
      accS += nrm; accQ += (double)nrm * (double)nrm;
    }
  }
  double oS = accS + __shfl_down(accS, 1, 64);
  double oQ = accQ + __shfl_down(accQ, 1, 64);
  if (hh == 0) {
    part[((size_t)s * 32 + o) * 2 + 0] = oS;
    part[((size_t)s * 32 + o) * 2 + 1] = oQ;
  }
}

__global__ __launch_bounds__(64) void k_l3_pass2(const float* X1, const float* X2,
    const float* Wf3g, const float* Wd3g, const float* g3, const float* b3, const float* st3,
    const float* Ws1fg, float* H3, double* part)
{
  __shared__ float x1ls[480], x2ls[480], h3ls[480], hm[96], d3ls[15];
  __shared__ float wd3[64];
  __shared__ float gls[32], bls[32], stls[64];
  int l = threadIdx.x;
  if (l < 64) wd3[l] = Wd3g[l];
  if (l < 32) { gls[l] = g3[l]; bls[l] = b3[l]; }
  if (l < 64) stls[l] = st3[l];
  int o = l >> 1, hh = l & 1;
  double accS = 0, accQ = 0;
  int s = blockIdx.x;
  __syncthreads();
  for (int r = l; r < 480; r += 64) { x1ls[r] = X1[(size_t)s * 480 + r]; x2ls[r] = X2[(size_t)s * 480 + r]; }
  __syncthreads();
  if (l < 15) {
    int j = l / 5, m = l % 5;
    float a = 0.f;
    for (int c = 0; c < 64; ++c) {
      const float* src = (c < 32) ? (x1ls + c * 15) : (x2ls + (c - 32) * 15);
      a += wd3[c] * src[j * 5 + m];
    }
    d3ls[l] = a;
  }
  __syncthreads();
  {
    int m0 = hh ? 3 : 0, mc = hh ? 2 : 3;
    float mean = stls[o * 2], rstd = stls[o * 2 + 1], gg = gls[o], bb = bls[o];
    const float* wrow = Wf3g + o * 64;
    for (int mi = 0; mi < mc; ++mi) {
      int m = m0 + mi;
      float p[3] = {0, 0, 0};
      for (int c = 0; c < 64; ++c) {
        float w = wrow[c];
        const float* src = (c < 32) ? (x1ls + c * 15) : (x2ls + (c - 32) * 15);
        p[0] += w * src[m]; p[1] += w * src[5 + m]; p[2] += w * src[10 + m];
      }
      float nrm = sqrtf(p[0] * p[0] + p[1] * p[1] + p[2] * p[2]) + 1e-6f;
      float dd[3] = {d3ls[m], d3ls[5 + m], d3ls[10 + m]};
      float outv[3];
      lrelu3(p, dd, nrm, mean, rstd, gg, bb, outv);
      h3ls[o * 15 + 0 + m] = outv[0];
      h3ls[o * 15 + 5 + m] = outv[1];
      h3ls[o * 15 + 10 + m] = outv[2];
      H3[(size_t)s * 480 + o * 15 + m] = outv[0];
      H3[(size_t)s * 480 + o * 15 + 5 + m] = outv[1];
      H3[(size_t)s * 480 + o * 15 + 10 + m] = outv[2];
    }
  }
  __syncthreads();
  for (int t = 0; t < 2; ++t) {
    int task = t * 64 + l;
    if (task < 96) {
      float a = h3ls[task * 5 + 0] + h3ls[task * 5 + 1] + h3ls[task * 5 + 2] + h3ls[task * 5 + 3] + h3ls[task * 5 + 4];
      hm[task] = a / 5.f;
    }
  }
  __syncthreads();
  {
    int m0 = hh ? 3 : 0, mc = hh ? 2 : 3;
    const float* wrow = Ws1fg + o * 64;
    for (int mi = 0; mi < mc; ++mi) {
      int m = m0 + mi;
      float p[3] = {0, 0, 0};
      for (int c = 0; c < 32; ++c) {
        float w = wrow[c];
        p[0] += w * h3ls[c * 15 + m]; p[1] += w * h3ls[c * 15 + 5 + m]; p[2] += w * h3ls[c * 15 + 10 + m];
      }
      for (int c = 0; c < 32; ++c) {
        float w = wrow[32 + c];
        p[0] += w * hm[c * 3 + 0]; p[1] += w * hm[c * 3 + 1]; p[2] += w * hm[c * 3 + 2];
      }
      float nrm = sqrtf(p[0] * p[0] + p[1] * p[1] + p[2] * p[2]) + 1e-6f;
      accS += nrm; accQ += (double)nrm * (double)nrm;
    }
  }
  double oS = accS + __shfl_down(accS, 1, 64);
  double oQ = accQ + __shfl_down(accQ, 1, 64);
  if (hh == 0) {
    part[((size_t)s * 32 + o) * 2 + 0] = oS;
    part[((size_t)s * 32 + o) * 2 + 1] = oQ;
  }
}

__global__ __launch_bounds__(64) void k_s1_pass2(const float* H3,
    const float* Ws1fg, const float* Ws1dg, const float* gs1, const float* bs1, const float* st4,
    const float* Ws2fg, float* Z1, float* part5)
{
  __shared__ float h3ls[480], hm[96], z1ls[480];
  __shared__ float gls[32], bls[32], stls[64];
  int l = threadIdx.x;
  if (l < 32) { gls[l] = gs1[l]; bls[l] = bs1[l]; }
  if (l < 64) stls[l] = st4[l];
  int o = l >> 1, hh = l & 1;
  double accS = 0, accQ = 0;
  int s = blockIdx.x;
  __syncthreads();
  for (int r = l; r < 480; r += 64) h3ls[r] = H3[(size_t)s * 480 + r];
  __syncthreads();
  for (int t = 0; t < 2; ++t) {
    int task = t * 64 + l;
    if (task < 96) {
      float a = h3ls[task * 5 + 0] + h3ls[task * 5 + 1] + h3ls[task * 5 + 2] + h3ls[task * 5 + 3] + h3ls[task * 5 + 4];
      hm[task] = a / 5.f;
    }
  }
  __syncthreads();
  {
    int m0 = hh ? 3 : 0, mc = hh ? 2 : 3;
    float mean = stls[o * 2], rstd = stls[o * 2 + 1], gg = gls[o], bb = bls[o];
    const float* wfrow = Ws1fg + o * 64;
    const float* wdrow = Ws1dg + o * 64;
    for (int mi = 0; mi < mc; ++mi) {
      int m = m0 + mi;
      float p[3] = {0, 0, 0}, dd[3] = {0, 0, 0};
      for (int c = 0; c < 32; ++c) {
        float wA = wfrow[c], wB = wdrow[c];
        float v0 = h3ls[c * 15 + m], v1 = h3ls[c * 15 + 5 + m], v2 = h3ls[c * 15 + 10 + m];
        p[0] += wA * v0; p[1] += wA * v1; p[2] += wA * v2;
        dd[0] += wB * v0; dd[1] += wB * v1; dd[2] += wB * v2;
      }
      for (int c = 0; c < 32; ++c) {
        float wA = wfrow[32 + c], wB = wdrow[32 + c];
        float v0 = hm[c * 3 + 0], v1 = hm[c * 3 + 1], v2 = hm[c * 3 + 2];
        p[0] += wA * v0; p[1] += wA * v1; p[2] += wA * v2;
        dd[0] += wB * v0; dd[1] += wB * v1; dd[2] += wB * v2;
      }
      float nrm = sqrtf(p[0] * p[0] + p[1] * p[1] + p[2] * p[2]) + 1e-6f;
      float outv[3];
      lrelu3(p, dd, nrm, mean, rstd, gg, bb, outv);
      z1ls[o * 15 + m] = outv[0];
      z1ls[o * 15 + 5 + m] = outv[1];
      z1ls[o * 15 + 10 + m] = outv[2];
      Z1[(size_t)s * 480 + o * 15 + m] = outv[0];
      Z1[(size_t)s * 480 + o * 15 + 5 + m] = outv[1];
      Z1[(size_t)s * 480 + o * 15 + 10 + m] = outv[2];
    }
  }
  __syncthreads();
  if (l < 32) {
    int m0 = hh ? 3 : 0, mc = hh ? 2 : 3;
    const float* wrow = Ws2fg + o * 32;
    for (int mi = 0; mi < mc; ++mi) {
      int m = m0 + mi;
      float p[3] = {0, 0, 0};
      for (int c = 0; c < 32; ++c) {
        float w = wrow[c];
        p[0] += w * z1ls[c * 15 + m]; p[1] += w * z1ls[c * 15 + 5 + m]; p[2] += w * z1ls[c * 15 + 10 + m];
      }
      float nrm = sqrtf(p[0] * p[0] + p[1] * p[1] + p[2] * p[2]) + 1e-6f;
      accS += nrm; accQ += (double)nrm * (double)nrm;
    }
  }
  double oS = accS + __shfl_down(accS, 1, 64);
  double oQ = accQ + __shfl_down(accQ, 1, 64);
  if (hh == 0 && l < 32) {
    part5[((size_t)s * 16 + o) * 2 + 0] = (float)oS;
    part5[((size_t)s * 16 + o) * 2 + 1] = (float)oQ;
  }
}

__global__ __launch_bounds__(64) void k_final(const float* Z1, const float* H3,
    const float* X1, const float* X2,
    const float* Ws2fg, const float* Ws2dg, const float* gs2, const float* bs2, const float* st5,
    const float* Wsling, const float* Wh1g, const float* bh1g, const float* Wh2g, const float* Wp3g,
    const float* scn, const float* rotn,
    float* out_hs, float* out_ks, float* ENT)
{
  __shared__ float z1ls[480], h3ls[480], x1ls[480], x2ls[480], hm[96];
  __shared__ float z2ls[240], z0ls[45], xmaxls[192];
  __shared__ float phsp[320], xmp[64];
  __shared__ float pooled[96], phsls[5];
  __shared__ double ddot[160], pkd[9];
  __shared__ float mat[25], mat2[25], scls[5], ssls[5];
  __shared__ int ordls[5];
  __shared__ float gls[16], bls[16], stls[32];
  int l = threadIdx.x;
  if (l < 16) { gls[l] = gs2[l]; bls[l] = bs2[l]; }
  if (l < 32) stls[l] = st5[l];
  float bh1v = bh1g[0];
  int o = l >> 1, hh = l & 1;
  int s = blockIdx.x;
  __syncthreads();
  for (int r = l; r < 480; r += 64) {
    z1ls[r] = Z1[(size_t)s * 480 + r];
    h3ls[r] = H3[(size_t)s * 480 + r];
    x1ls[r] = X1[(size_t)s * 480 + r];
    x2ls[r] = X2[(size_t)s * 480 + r];
  }
  __syncthreads();
  if (l < 32) {
    int m0 = hh ? 3 : 0, mc = hh ? 2 : 3;
    float mean = stls[o * 2], rstd = stls[o * 2 + 1], gg = gls[o], bb = bls[o];
    const float* wfrow = Ws2fg + o * 32;
    const float* wdrow = Ws2dg + o * 32;
    for (int mi = 0; mi < mc; ++mi) {
      int m = m0 + mi;
      float p[3] = {0, 0, 0}, dd[3] = {0, 0, 0};
      for (int c = 0; c < 32; ++c) {
        float wA = wfrow[c], wB = wdrow[c];
        float v0 = z1ls[c * 15 + m], v1 = z1ls[c * 15 + 5 + m], v2 = z1ls[c * 15 + 10 + m];
        p[0] += wA * v0; p[1] += wA * v1; p[2] += wA * v2;
        dd[0] += wB * v0; dd[1] += wB * v1; dd[2] += wB * v2;
      }
      float nrm = sqrtf(p[0] * p[0] + p[1] * p[1] + p[2] * p[2]) + 1e-6f;
      float outv[3];
      lrelu3(p, dd, nrm, mean, rstd, gg, bb, outv);
      z2ls[o * 15 + m] = outv[0];
      z2ls[o * 15 + 5 + m] = outv[1];
      z2ls[o * 15 + 10 + m] = outv[2];
    }
  }
  for (int t = 0; t < 2; ++t) {
    int task = t * 64 + l;
    if (task < 96) {
      float a = h3ls[task * 5 + 0] + h3ls[task * 5 + 1] + h3ls[task * 5 + 2] + h3ls[task * 5 + 3] + h3ls[task * 5 + 4];
      hm[task] = a / 5.f;
    }
  }
  __syncthreads();
  if (l < 45) {
    int j = l / 15, kk = (l / 5) % 3, m = l % 5;
    float a = 0.f;
    for (int c = 0; c < 16; ++c) a += Wsling[j * 16 + c] * z2ls[c * 15 + kk * 5 + m];
    z0ls[l] = a;
  }
  __syncthreads();
  for (int t = 0; t < 3; ++t) {
    int r = t * 64 + l;
    if (r < 192) {
      int i = r / 3, kk = r % 3;
      float vmax = -3.4e38f;
      for (int m = 0; m < 5; ++m) {
        float v = 0.f;
        #pragma unroll
        for (int j = 0; j < 3; ++j) {
          float hv = (i < 32) ? h3ls[i * 15 + j * 5 + m] : hm[(i - 32) * 3 + j];
          v += hv * z0ls[(j * 3 + kk) * 5 + m];
        }
        vmax = fmaxf(vmax, v);
      }
      xmaxls[r] = vmax;
    }
  }
  __syncthreads();
  {
    float xmacc = 0.f;
    float pacc[5] = {0, 0, 0, 0, 0};
    for (int rr = l; rr < 192; rr += 64) {
      xmacc += Wh1g[rr] * xmaxls[rr];
      int i = rr / 3, kk = rr % 3;
      float w = Wh1g[192 + rr];
      for (int m = 0; m < 5; ++m) {
        float v = 0.f;
        #pragma unroll
        for (int j = 0; j < 3; ++j) {
          float xv = (i < 32) ? x1ls[i * 15 + j * 5 + m] : x2ls[(i - 32) * 15 + j * 5 + m];
          v += xv * z0ls[(j * 3 + kk) * 5 + m];
        }
        pacc[m] += w * v;
      }
    }
    xmp[l] = xmacc;
    #pragma unroll
    for (int m = 0; m < 5; ++m) phsp[m * 64 + l] = pacc[m];
  }
  __syncthreads();
  if (l < 5) {
    float xs = 0.f;
    for (int k2 = 0; k2 < 64; ++k2) xs += xmp[k2];
    float a = 0.f;
    for (int k2 = 0; k2 < 64; ++k2) a += phsp[l * 64 + k2];
    phsls[l] = xs + a + bh1v;
  }
  // pooled dots in double: 3 independent accumulators per task (ILP),
  // per-j c2-ascending order identical to reference.
  for (int t = 0; t < 3; ++t) {
    int task = t * 64 + l;
    if (task < 160) {
      int cc = task & 31, m = task >> 5;
      const float* wrow = Wp3g + cc * 32;
      double accj[3] = {0.0, 0.0, 0.0};
      for (int c2 = 0; c2 < 32; ++c2) {
        double w = (double)wrow[c2];
        #pragma unroll
        for (int j = 0; j < 3; ++j)
          accj[j] += w * (double)x1ls[c2 * 15 + j * 5 + m];
      }
      double acc = 0.0;
      #pragma unroll
      for (int j = 0; j < 3; ++j)
        acc += (double)x1ls[cc * 15 + j * 5 + m] * accj[j];
      ddot[cc * 5 + m] = acc;
    }
  }
  __syncthreads();
  if (l < 32) {
    double best = -1e300; int bi = 0;
    for (int m = 0; m < 5; ++m) { double v = ddot[l * 5 + m]; if (v > best) { best = v; bi = m; } }
    pooled[l * 3 + 0] = x1ls[l * 15 + bi];
    pooled[l * 3 + 1] = x1ls[l * 15 + 5 + bi];
    pooled[l * 3 + 2] = x1ls[l * 15 + 10 + bi];
  }
  __syncthreads();
  if (l < 9) {
    int o2 = l / 3, i = l % 3;
    double a = 0.0;
    for (int c = 0; c < 32; ++c) a += (double)Wh2g[o2 * 32 + c] * (double)pooled[c * 3 + i];
    pkd[i * 3 + o2] = a;
  }
  if (l < 5) scls[l] = phsls[l] + scn[(size_t)s * 5 + l];
  __syncthreads();
  if (l < 5) {
    float nr = sqrtf(scls[0] * scls[0] + scls[1] * scls[1] + scls[2] * scls[2] + scls[3] * scls[3] + scls[4] * scls[4]);
    float v = scls[l] / fmaxf(nr, 1e-12f);
    __syncthreads();
    scls[l] = v;
  } else { __syncthreads(); }
  __syncthreads();
  if (l == 0) {
    unsigned chosen = 0u;
    for (int r = 0; r < 5; ++r) {
      float best = -3.4e38f; int bi = 0;
      for (int n = 0; n < 5; ++n) {
        if ((chosen >> n) & 1u) continue;
        if (scls[n] > best) { best = scls[n]; bi = n; }
      }
      ordls[r] = bi; ssls[r] = best; chosen |= (1u << bi);
    }
  }
  __syncthreads();
  float lp = 0.f;
  if (l < 25) {
    int i = l / 5, j = l % 5;
    lp = -fabsf(scls[i] - ssls[j]) / 0.01f;
  }
  for (int itn = 0; itn < 20; ++itn) {
    if (l < 25) mat[l] = lp;
    __syncthreads();
    if (l < 25) {
      int i = l / 5;
      float m0 = mat[i * 5], m1 = mat[i * 5 + 1], m2 = mat[i * 5 + 2], m3 = mat[i * 5 + 3], m4 = mat[i * 5 + 4];
      float mx = fmaxf(fmaxf(fmaxf(m0, m1), fmaxf(m2, m3)), m4);
      float ssum = expf(m0 - mx) + expf(m1 - mx) + expf(m2 - mx) + expf(m3 - mx) + expf(m4 - mx);
      lp -= (mx + logf(ssum));
    }
    __syncthreads();
    if (l < 25) mat[l] = lp;
    __syncthreads();
    if (l < 25) {
      int j = l % 5;
      float m0 = mat[j], m1 = mat[5 + j], m2 = mat[10 + j], m3 = mat[15 + j], m4 = mat[20 + j];
      float mx = fmaxf(fmaxf(fmaxf(m0, m1), fmaxf(m2, m3)), m4);
      float ssum = expf(m0 - mx) + expf(m1 - mx) + expf(m2 - mx) + expf(m3 - mx) + expf(m4 - mx);
      lp -= (mx + logf(ssum));
    }
    __syncthreads();
  }
  float soft = 0.f;
  if (l < 25) {
    int i = l / 5, j = l % 5;
    soft = expf(lp);
    float hard = (ordls[j] == i) ? 1.f : 0.f;
    out_hs[(size_t)s * 25 + l] = (hard - soft) + soft;
    mat[l] = fmaxf(soft, 1e-12f);
  }
  __syncthreads();
  if (l < 25) {
    int i = l / 5, j = l % 5;
    float scl = mat[l];
    float colsum = mat[j] + mat[5 + j] + mat[10 + j] + mat[15 + j] + mat[20 + j];
    float rowsum = mat[i * 5] + mat[i * 5 + 1] + mat[i * 5 + 2] + mat[i * 5 + 3] + mat[i * 5 + 4];
    float pc = scl / fmaxf(colsum, 1e-12f);
    float pr = scl / fmaxf(rowsum, 1e-12f);
    float t2 = -pc * fmaxf(logf(pc), -100.f);
    float t3 = -pr * fmaxf(logf(pr), -100.f);
    mat2[l] = t2 + t3;
  }
  __syncthreads();
  if (l == 0) {
    float a = 0.f;
    for (int k2 = 0; k2 < 25; ++k2) a += mat2[k2];
    ENT[s] = a;
    double M[9];
    #pragma unroll
    for (int r = 0; r < 9; ++r) M[r] = pkd[r] + (double)rotn[(size_t)s * 9 + r];
    double a0 = M[0], a1 = M[3], a2 = M[6];
    double n0 = sqrt(a0 * a0 + a1 * a1 + a2 * a2) + 1e-12;
    double e10 = a0 / n0, e11 = a1 / n0, e12 = a2 / n0;
    double b0 = M[1], b1 = M[4], b2 = M[7];
    double t1 = e10 * b0 + e11 * b1 + e12 * b2;
    double v20 = b0 - t1 * e10, v21 = b1 - t1 * e11, v22 = b2 - t1 * e12;
    double n2 = sqrt(v20 * v20 + v21 * v21 + v22 * v22) + 1e-12;
    double e20 = v20 / n2, e21 = v21 / n2, e22 = v22 / n2;
    double c0 = M[2], c1 = M[5], c2 = M[8];
    double ta = e10 * c0 + e11 * c1 + e12 * c2;
    double tb = e20 * c0 + e21 * c1 + e22 * c2;
    double v30 = c0 - ta * e10 - tb * e20, v31 = c1 - ta * e11 - tb * e21, v32 = c2 - ta * e12 - tb * e22;
    double n3 = sqrt(v30 * v30 + v31 * v31 + v32 * v32) + 1e-12;
    double e30 = v30 / n3, e31 = v31 / n3, e32 = v32 / n3;
    float* dst = out_ks + (size_t)s * 9;
    dst[0] = (float)e10; dst[1] = (float)e20; dst[2] = (float)e30;
    dst[3] = (float)e11; dst[4] = (float)e21; dst[5] = (float)e31;
    dst[6] = (float)e12; dst[7] = (float)e22; dst[8] = (float)e32;
  }
}

__global__ __launch_bounds__(256) void k_ent_red(const float* ENT, float* outp)
{
  __shared__ double red[256];
  int t = threadIdx.x;
  double a = 0;
  for (int i = t; i < 8192; i += 256) a += (double)ENT[i];
  red[t] = a;
  __syncthreads();
  if (t == 0) {
    double sum = 0;
    for (int k = 0; k < 256; ++k) sum += red[k];
    outp[0] = (float)(sum / 40960.0);
  }
}

// ---------------------------------------------------------------- launch

extern "C" void kernel_launch(void* const* d_in, const int* in_sizes, int n_in,
                              void* d_out, int out_size, void* d_ws, size_t ws_size,
                              hipStream_t stream)
{
  (void)in_sizes; (void)n_in; (void)out_size;
  const float* nf    = (const float*)d_in[0];
  const float* noise = (const float*)d_in[1];
  const float* scn   = (const float*)d_in[2];
  const float* rotn  = (const float*)d_in[3];
  const float* Wf1 = (const float*)d_in[4],  *Wd1 = (const float*)d_in[5];
  const float* g1  = (const float*)d_in[6],  *b1  = (const float*)d_in[7];
  const float* Wf2 = (const float*)d_in[8],  *Wd2 = (const float*)d_in[9];
  const float* g2  = (const float*)d_in[10], *b2  = (const float*)d_in[11];
  const float* Wf3 = (const float*)d_in[12], *Wd3 = (const float*)d_in[13];
  const float* g3  = (const float*)d_in[14], *b3  = (const float*)d_in[15];
  const float* Wp1 = (const float*)d_in[16], *Wp2 = (const float*)d_in[17], *Wp3 = (const float*)d_in[18];
  const float* Ws1f = (const float*)d_in[19], *Ws1d = (const float*)d_in[20];
  const float* gs1  = (const float*)d_in[21], *bs1  = (const float*)d_in[22];
  const float* Ws2f = (const float*)d_in[23], *Ws2d = (const float*)d_in[24];
  const float* gs2  = (const float*)d_in[25], *bs2  = (const float*)d_in[26];
  const float* Wslin = (const float*)d_in[27];
  const float* Wh1   = (const float*)d_in[28];
  const float* bh1   = (const float*)d_in[29];
  const float* Wh2   = (const float*)d_in[30];

  // workspace layout (total 63,997,184 B):
  //   X1, X2, H3, Z1 : 4 x 15,728,640 B
  //   ENT            : 32,768 B   (doubles as RED1 scratch)
  //   ST             : 1,280 B
  //   legacy slot    : 1,048,576 B (PART5 float pairs)
  // PART_main (4 MB doubles) aliases the head of Z1 (dead until k_s1_pass2).
  const size_t SZ = (size_t)8192 * 480;
  if (ws_size < 63997184ull) return;
  float* ws  = (float*)d_ws;
  float* X1  = ws;
  float* X2  = X1 + SZ;
  float* H3  = X2 + SZ;
  float* Z1  = H3 + SZ;
  float* ENT = Z1 + SZ;
  float* ST  = ENT + 8192;
  float* PART5 = ST + 320;
  double* PARTm = (double*)Z1;
  double* RED1  = (double*)ENT;
  float* st1 = ST, *st2 = ST + 64, *st3 = ST + 128, *st4 = ST + 192, *st5 = ST + 256;

  float* out_hs = (float*)d_out;
  float* out_ks = out_hs + 204800;
  float* out_sc = out_hs + 278528;

  dim3 grid(NSAMP), blk(64);
  k_l1_pass1<<<grid, blk, 0, stream>>>(nf, noise, Wf1, PARTm);
  k_red1<<<64, 64, 0, stream>>>(PARTm, RED1, 32);
  k_red2<<<1, 64, 0, stream>>>(RED1, st1, 32, 163840.f);
  k_l1_pass2<<<grid, blk, 0, stream>>>(nf, noise, Wf1, Wd1, g1, b1, st1, Wp1, Wf2, X1, PARTm);
  k_red1<<<64, 64, 0, stream>>>(PARTm, RED1, 32);
  k_red2<<<1, 64, 0, stream>>>(RED1, st2, 32, 163840.f);
  k_l2_pass2<<<grid, blk, 0, stream>>>(X1, Wf2, Wd2, g2, b2, st2, Wp2, Wf3, X2, PARTm);
  k_red1<<<64, 64, 0, stream>>>(PARTm, RED1, 32);
  k_red2<<<1, 64, 0, stream>>>(RED1, st3, 32, 40960.f);
  k_l3_pass2<<<grid, blk, 0, stream>>>(X1, X2, Wf3, Wd3, g3, b3, st3, Ws1f, H3, PARTm);
  k_red1<<<64, 64, 0, stream>>>(PARTm, RED1, 32);
  k_red2<<<1, 64, 0, stream>>>(RED1, st4, 32, 40960.f);
  k_s1_pass2<<<grid, blk, 0, stream>>>(H3, Ws1f, Ws1d, gs1, bs1, st4, Ws2f, Z1, PART5);
  k_red1f<<<64, 64, 0, stream>>>(PART5, RED1, 16);
  k_red2<<<1, 64, 0, stream>>>(RED1, st5, 16, 40960.f);
  k_final<<<grid, blk, 0, stream>>>(Z1, H3, X1, X2, Ws2f, Ws2d, gs2, bs2, st5,
                                    Wslin, Wh1, bh1, Wh2, Wp3, scn, rotn,
                                    out_hs, out_ks, ENT);
  k_ent_red<<<1, 256, 0, stream>>>(ENT, out_sc);
}

// Round 11
// 610.841 us; speedup vs baseline: 1.5499x; 1.0880x over previous
//
#include <hip/hip_runtime.h>
#include <math.h>

#define NSAMP 8192   // one block per sample

// LDS padding strides
#define WS4  5    // [32][4] weights
#define HS   21   // h1/h2 row stride (logical 20)

// ---------------------------------------------------------------- helpers

__device__ __forceinline__ void knn_compute(const float* xls, int C3, float* dls, int* idxls, int l)
{
  if (l < 25) {
    int m = l / 5, n = l % 5;
    float acc = 0.f;
    for (int r = 0; r < C3; ++r) acc += xls[r * 5 + m] * xls[r * 5 + n];
    dls[l] = acc;  // inner
  }
  __syncthreads();
  float dm = 0.f, dn = 0.f, inn = 0.f;
  if (l < 25) { int m = l / 5, n = l % 5; dm = dls[m * 5 + m]; dn = dls[n * 5 + n]; inn = dls[l]; }
  __syncthreads();
  if (l < 25) dls[l] = 2.f * inn - dm - dn;
  __syncthreads();
  if (l < 5) {
    int m = l; unsigned chosen = 0u;
    for (int kk = 0; kk < 4; ++kk) {
      float best = -3.4e38f; int bi = 0;
      for (int n = 0; n < 5; ++n) {
        if ((chosen >> n) & 1u) continue;
        float v = dls[m * 5 + n];
        if (v > best) { best = v; bi = n; }
      }
      idxls[m * 4 + kk] = bi;
      chosen |= (1u << bi);
    }
  }
  __syncthreads();
}

template<bool WD>
__device__ __forceinline__ void feat_pd2(const float* xls, const int* idxls,
    const float* Wf, const float* Wd, int o, int m, int kk, float* p, float* d)
{
  const int nb = idxls[m * 4 + kk];
  const float* wf = Wf + o * WS4;
  const float* wd = WD ? (Wd + o * WS4) : wf;
  for (int c = 0; c < 2; ++c) {
    float wfc = wf[c];
    float wdc = WD ? wd[c] : 0.f;
    #pragma unroll
    for (int j = 0; j < 3; ++j) {
      float v = xls[c * 15 + j * 5 + nb] - xls[c * 15 + j * 5 + m];
      p[j] += wfc * v;
      if (WD) d[j] += wdc * v;
    }
  }
  for (int c = 0; c < 2; ++c) {
    float wfc = wf[2 + c];
    float wdc = WD ? wd[2 + c] : 0.f;
    #pragma unroll
    for (int j = 0; j < 3; ++j) {
      float v = xls[c * 15 + j * 5 + m];
      p[j] += wfc * v;
      if (WD) d[j] += wdc * v;
    }
  }
}

__device__ __forceinline__ void lrelu3(const float* p, const float* d, float nrm,
    float mean, float rstd, float g, float b, float* out)
{
  float nbn = g * (nrm - mean) * rstd + b;
  float s = nbn / nrm;
  float pb0 = p[0] * s, pb1 = p[1] * s, pb2 = p[2] * s;
  float dot = pb0 * d[0] + pb1 * d[1] + pb2 * d[2];
  if (dot >= 0.f) { out[0] = pb0; out[1] = pb1; out[2] = pb2; }
  else {
    float dsq = d[0] * d[0] + d[1] * d[1] + d[2] * d[2];
    float f = 0.8f * (dot / (dsq + 1e-6f));
    out[0] = pb0 - f * d[0]; out[1] = pb1 - f * d[1]; out[2] = pb2 - f * d[2];
  }
}

__device__ __forceinline__ void load_x_sample(const float* nf, const float* noise, int s, int l, float* xls)
{
  if (l < 30) {
    int c = l / 15, j = (l / 5) % 3, m = l % 5, b = s >> 6;
    xls[l] = nf[((b * 5 + m) * 3 + j) * 2 + c] + noise[(((size_t)s * 5 + m) * 3 + j) * 2 + c];
  }
}

// maxpool with 12 independent accumulators (ILP) — bit-identical order.
__device__ __forceinline__ void maxpool_task(const float* Wg, const float* H,
    int oo, int m, int* bi_out)
{
  const float* wrow = Wg + oo * 32;
  float acc[4][3];
  #pragma unroll
  for (int kk = 0; kk < 4; ++kk)
    #pragma unroll
    for (int j = 0; j < 3; ++j) acc[kk][j] = 0.f;
  for (int c = 0; c < 32; ++c) {
    float w = wrow[c];
    #pragma unroll
    for (int j = 0; j < 3; ++j) {
      const float* hrow = H + (c * 3 + j) * HS + m * 4;
      #pragma unroll
      for (int kk = 0; kk < 4; ++kk) acc[kk][j] += w * hrow[kk];
    }
  }
  float best = -3.4e38f; int bi = 0;
  #pragma unroll
  for (int kk = 0; kk < 4; ++kk) {
    float a2 = 0.f;
    #pragma unroll
    for (int j = 0; j < 3; ++j) a2 += H[(oo * 3 + j) * HS + m * 4 + kk] * acc[kk][j];
    if (a2 > best) { best = a2; bi = kk; }
  }
  *bi_out = bi;
}

// ---------------------------------------------------------------- kernels

__global__ __launch_bounds__(64) void k_l1_pass1(const float* nf, const float* noise,
    const float* Wf1, double* part)
{
  __shared__ float xls[30], dls[25], wf[32 * WS4];
  __shared__ int idxls[20];
  int l = threadIdx.x;
  for (int r = l; r < 128; r += 64) wf[(r >> 2) * WS4 + (r & 3)] = Wf1[r];
  int o = l >> 1, hh = l & 1;
  double accS = 0, accQ = 0;
  int s = blockIdx.x;
  __syncthreads();
  load_x_sample(nf, noise, s, l, xls);
  __syncthreads();
  knn_compute(xls, 6, dls, idxls, l);
  for (int t = 0; t < 10; ++t) {
    int e = hh * 10 + t; int m = e >> 2, kk = e & 3;
    float p[3] = {0, 0, 0}, dum[3];
    feat_pd2<false>(xls, idxls, wf, wf, o, m, kk, p, dum);
    float nrm = sqrtf(p[0] * p[0] + p[1] * p[1] + p[2] * p[2]) + 1e-6f;
    accS += nrm; accQ += (double)nrm * (double)nrm;
  }
  double oS = accS + __shfl_down(accS, 1, 64);
  double oQ = accQ + __shfl_down(accQ, 1, 64);
  if (hh == 0) {
    part[((size_t)s * 32 + o) * 2 + 0] = oS;
    part[((size_t)s * 32 + o) * 2 + 1] = oQ;
  }
}

// two-stage deterministic reduce
__global__ __launch_bounds__(64) void k_red1(const double* part, double* red1, int C)
{
  int p = threadIdx.x, b = blockIdx.x;
  double acc = 0;
  if (p < 2 * C) {
    int o = p >> 1, q = p & 1;
    for (int g = b * 128; g < (b + 1) * 128; ++g)
      acc += part[((size_t)g * C + o) * 2 + q];
  }
  red1[b * 64 + p] = acc;
}

__global__ __launch_bounds__(64) void k_red1f(const float* part, double* red1, int C)
{
  int p = threadIdx.x, b = blockIdx.x;
  double acc = 0;
  if (p < 2 * C) {
    int o = p >> 1, q = p & 1;
    for (int g = b * 128; g < (b + 1) * 128; ++g)
      acc += (double)part[((size_t)g * C + o) * 2 + q];
  }
  red1[b * 64 + p] = acc;
}

__global__ __launch_bounds__(64) void k_red2(const double* red1, float* stats, int C, float count)
{
  __shared__ double tot[64];
  int p = threadIdx.x;
  double a = 0;
  if (p < 2 * C) for (int b = 0; b < 64; ++b) a += red1[b * 64 + p];
  tot[p] = a;
  __syncthreads();
  if (p < C) {
    double sum = tot[p * 2 + 0], ssq = tot[p * 2 + 1];
    double mean = sum / (double)count;
    double var = ssq / (double)count - mean * mean;
    stats[p * 2 + 0] = (float)mean;
    stats[p * 2 + 1] = (float)(1.0 / sqrt(var + 1e-5));
  }
}

// layer1 pass2 (h1, maxpool->x1) + layer2 pass1 stats via A/B factorization
__global__ __launch_bounds__(64) void k_l1_pass2(const float* nf, const float* noise,
    const float* Wf1g, const float* Wd1g, const float* g1, const float* b1, const float* st1,
    const float* Wp1g, const float* Wf2g, float* X1, double* part)
{
  __shared__ float xls[30], dls[25], h1[96 * HS];
  __shared__ __align__(16) float x1ls[480];
  __shared__ float wf1[32 * WS4], wd1[32 * WS4];
  __shared__ float AB2[960];
  __shared__ float gls[32], bls[32], stls[64];
  __shared__ int idxls[20], idx2[20];
  int l = threadIdx.x;
  for (int r = l; r < 128; r += 64) { int q = (r >> 2) * WS4 + (r & 3); wf1[q] = Wf1g[r]; wd1[q] = Wd1g[r]; }
  if (l < 32) { gls[l] = g1[l]; bls[l] = b1[l]; }
  if (l < 64) stls[l] = st1[l];
  int o = l >> 1, hh = l & 1;
  double accS = 0, accQ = 0;
  int s = blockIdx.x;
  __syncthreads();
  load_x_sample(nf, noise, s, l, xls);
  __syncthreads();
  knn_compute(xls, 6, dls, idxls, l);
  {
    float mean = stls[o * 2], rstd = stls[o * 2 + 1], gg = gls[o], bb = bls[o];
    for (int t = 0; t < 10; ++t) {
      int e = hh * 10 + t; int m = e >> 2, kk = e & 3;
      float p[3] = {0, 0, 0}, dd[3] = {0, 0, 0};
      feat_pd2<true>(xls, idxls, wf1, wd1, o, m, kk, p, dd);
      float nrm = sqrtf(p[0] * p[0] + p[1] * p[1] + p[2] * p[2]) + 1e-6f;
      float outv[3];
      lrelu3(p, dd, nrm, mean, rstd, gg, bb, outv);
      h1[(o * 3 + 0) * HS + m * 4 + kk] = outv[0];
      h1[(o * 3 + 1) * HS + m * 4 + kk] = outv[1];
      h1[(o * 3 + 2) * HS + m * 4 + kk] = outv[2];
    }
  }
  __syncthreads();
  for (int t = 0; t < 3; ++t) {
    int task = t * 64 + l;
    if (task < 160) {
      int oo = task & 31, m = task >> 5;
      int bi;
      maxpool_task(Wp1g, h1, oo, m, &bi);
      for (int j = 0; j < 3; ++j) {
        float v = h1[(oo * 3 + j) * HS + m * 4 + bi];
        x1ls[(oo * 3 + j) * 5 + m] = v;
        X1[(size_t)s * 480 + (oo * 3 + j) * 5 + m] = v;
      }
    }
  }
  __syncthreads();
  knn_compute(x1ls, 96, dls, idx2, l);
  {
    float acc[15];
    #pragma unroll
    for (int r = 0; r < 15; ++r) acc[r] = 0.f;
    const float* wrow = Wf2g + o * 64 + hh * 32;
    for (int c = 0; c < 32; ++c) {
      float wc = wrow[c];
      #pragma unroll
      for (int r = 0; r < 15; ++r) acc[r] += wc * x1ls[c * 15 + r];
    }
    #pragma unroll
    for (int r = 0; r < 15; ++r) AB2[hh * 480 + o * 15 + r] = acc[r];
  }
  __syncthreads();
  {
    const float* A2 = AB2 + o * 15;
    const float* B2 = AB2 + 480 + o * 15;
    for (int t = 0; t < 10; ++t) {
      int e = hh * 10 + t; int m = e >> 2, kk = e & 3;
      int nb = idx2[m * 4 + kk];
      float p0 = A2[nb] - A2[m] + B2[m];
      float p1 = A2[5 + nb] - A2[5 + m] + B2[5 + m];
      float p2 = A2[10 + nb] - A2[10 + m] + B2[10 + m];
      float nrm = sqrtf(p0 * p0 + p1 * p1 + p2 * p2) + 1e-6f;
      accS += nrm; accQ += (double)nrm * (double)nrm;
    }
  }
  double oS = accS + __shfl_down(accS, 1, 64);
  double oQ = accQ + __shfl_down(accQ, 1, 64);
  if (hh == 0) {
    part[((size_t)s * 32 + o) * 2 + 0] = oS;
    part[((size_t)s * 32 + o) * 2 + 1] = oQ;
  }
}

// layer2 pass2 via A/B factorization + maxpool + layer3 pass1 stats
__global__ __launch_bounds__(64) void k_l2_pass2(const float* X1,
    const float* Wf2g, const float* Wd2g, const float* g2, const float* b2, const float* st2,
    const float* Wp2g, const float* Wf3g, float* X2, double* part)
{
  __shared__ __align__(16) float x1ls[480];
  __shared__ float dls[25], h2[96 * HS], x2ls[480];
  __shared__ float ABls[1920];
  __shared__ float gls[32], bls[32], stls[64];
  __shared__ int idx2[20];
  int l = threadIdx.x;
  if (l < 32) { gls[l] = g2[l]; bls[l] = b2[l]; }
  if (l < 64) stls[l] = st2[l];
  int o = l >> 1, hh = l & 1;
  double accS = 0, accQ = 0;
  int s = blockIdx.x;
  __syncthreads();
  {
    const float4* src = (const float4*)(X1 + (size_t)s * 480);
    float4* dst = (float4*)x1ls;
    for (int r = l; r < 120; r += 64) dst[r] = src[r];
  }
  __syncthreads();
  knn_compute(x1ls, 96, dls, idx2, l);
  {
    float accF[15], accD[15];
    #pragma unroll
    for (int r = 0; r < 15; ++r) { accF[r] = 0.f; accD[r] = 0.f; }
    const float* wfrow = Wf2g + o * 64 + hh * 32;
    const float* wdrow = Wd2g + o * 64 + hh * 32;
    for (int c = 0; c < 32; ++c) {
      float wfc = wfrow[c], wdc = wdrow[c];
      #pragma unroll
      for (int r = 0; r < 15; ++r) {
        float xv = x1ls[c * 15 + r];
        accF[r] += wfc * xv;
        accD[r] += wdc * xv;
      }
    }
    #pragma unroll
    for (int r = 0; r < 15; ++r) {
      ABls[hh * 480 + o * 15 + r] = accF[r];
      ABls[960 + hh * 480 + o * 15 + r] = accD[r];
    }
  }
  __syncthreads();
  {
    float mean = stls[o * 2], rstd = stls[o * 2 + 1], gg = gls[o], bb = bls[o];
    const float* Af = ABls + o * 15;
    const float* Bf = ABls + 480 + o * 15;
    const float* Ad = ABls + 960 + o * 15;
    const float* Bd = ABls + 1440 + o * 15;
    for (int t = 0; t < 10; ++t) {
      int e = hh * 10 + t; int m = e >> 2, kk = e & 3;
      int nb = idx2[m * 4 + kk];
      float p[3], dd[3];
      #pragma unroll
      for (int j = 0; j < 3; ++j) {
        p[j]  = Af[j * 5 + nb] - Af[j * 5 + m] + Bf[j * 5 + m];
        dd[j] = Ad[j * 5 + nb] - Ad[j * 5 + m] + Bd[j * 5 + m];
      }
      float nrm = sqrtf(p[0] * p[0] + p[1] * p[1] + p[2] * p[2]) + 1e-6f;
      float outv[3];
      lrelu3(p, dd, nrm, mean, rstd, gg, bb, outv);
      h2[(o * 3 + 0) * HS + m * 4 + kk] = outv[0];
      h2[(o * 3 + 1) * HS + m * 4 + kk] = outv[1];
      h2[(o * 3 + 2) * HS + m * 4 + kk] = outv[2];
    }
  }
  __syncthreads();
  for (int t = 0; t < 3; ++t) {
    int task = t * 64 + l;
    if (task < 160) {
      int oo = task & 31, m = task >> 5;
      int bi;
      maxpool_task(Wp2g, h2, oo, m, &bi);
      for (int j = 0; j < 3; ++j) {
        float v = h2[(oo * 3 + j) * HS + m * 4 + bi];
        x2ls[(oo * 3 + j) * 5 + m] = v;
        X2[(size_t)s * 480 + (oo * 3 + j) * 5 + m] = v;
      }
    }
  }
  __syncthreads();
  {
    int m0 = hh ? 3 : 0, mc = hh ? 2 : 3;
    for (int mi = 0; mi < mc; ++mi) {
      int m = m0 + mi;
      float p[3] = {0, 0, 0};
      for (int c = 0; c < 64; ++c) {
        float w = Wf3g[o * 64 + c];
        const float* src = (c < 32) ? (x1ls + c * 15) : (x2ls + (c - 32) * 15);
        p[0] += w * src[m]; p[1] += w * src[5 + m]; p[2] += w * src[10 + m];
      }
      float nrm = sqrtf(p[0] * p[0] + p[1] * p[1] + p[2] * p[2]) + 1e-6f;
      accS += nrm; accQ += (double)nrm * (double)nrm;
    }
  }
  double oS = accS + __shfl_down(accS, 1, 64);
  double oQ = accQ + __shfl_down(accQ, 1, 64);
  if (hh == 0) {
    part[((size_t)s * 32 + o) * 2 + 0] = oS;
    part[((size_t)s * 32 + o) * 2 + 1] = oQ;
  }
}

__global__ __launch_bounds__(64) void k_l3_pass2(const float* X1, const float* X2,
    const float* Wf3g, const float* Wd3g, const float* g3, const float* b3, const float* st3,
    const float* Ws1fg, float* H3, double* part)
{
  __shared__ __align__(16) float x1ls[480];
  __shared__ __align__(16) float x2ls[480];
  __shared__ float h3ls[480], hm[96], d3ls[15];
  __shared__ float wd3[64];
  __shared__ float gls[32], bls[32], stls[64];
  int l = threadIdx.x;
  if (l < 64) wd3[l] = Wd3g[l];
  if (l < 32) { gls[l] = g3[l]; bls[l] = b3[l]; }
  if (l < 64) stls[l] = st3[l];
  int o = l >> 1, hh = l & 1;
  double accS = 0, accQ = 0;
  int s = blockIdx.x;
  __syncthreads();
  {
    const float4* s1 = (const float4*)(X1 + (size_t)s * 480);
    const float4* s2 = (const float4*)(X2 + (size_t)s * 480);
    float4* d1 = (float4*)x1ls;
    float4* d2 = (float4*)x2ls;
    for (int r = l; r < 120; r += 64) { d1[r] = s1[r]; d2[r] = s2[r]; }
  }
  __syncthreads();
  if (l < 15) {
    int j = l / 5, m = l % 5;
    float a = 0.f;
    for (int c = 0; c < 64; ++c) {
      const float* src = (c < 32) ? (x1ls + c * 15) : (x2ls + (c - 32) * 15);
      a += wd3[c] * src[j * 5 + m];
    }
    d3ls[l] = a;
  }
  __syncthreads();
  {
    int m0 = hh ? 3 : 0, mc = hh ? 2 : 3;
    float mean = stls[o * 2], rstd = stls[o * 2 + 1], gg = gls[o], bb = bls[o];
    const float* wrow = Wf3g + o * 64;
    for (int mi = 0; mi < mc; ++mi) {
      int m = m0 + mi;
      float p[3] = {0, 0, 0};
      for (int c = 0; c < 64; ++c) {
        float w = wrow[c];
        const float* src = (c < 32) ? (x1ls + c * 15) : (x2ls + (c - 32) * 15);
        p[0] += w * src[m]; p[1] += w * src[5 + m]; p[2] += w * src[10 + m];
      }
      float nrm = sqrtf(p[0] * p[0] + p[1] * p[1] + p[2] * p[2]) + 1e-6f;
      float dd[3] = {d3ls[m], d3ls[5 + m], d3ls[10 + m]};
      float outv[3];
      lrelu3(p, dd, nrm, mean, rstd, gg, bb, outv);
      h3ls[o * 15 + 0 + m] = outv[0];
      h3ls[o * 15 + 5 + m] = outv[1];
      h3ls[o * 15 + 10 + m] = outv[2];
      H3[(size_t)s * 480 + o * 15 + m] = outv[0];
      H3[(size_t)s * 480 + o * 15 + 5 + m] = outv[1];
      H3[(size_t)s * 480 + o * 15 + 10 + m] = outv[2];
    }
  }
  __syncthreads();
  for (int t = 0; t < 2; ++t) {
    int task = t * 64 + l;
    if (task < 96) {
      float a = h3ls[task * 5 + 0] + h3ls[task * 5 + 1] + h3ls[task * 5 + 2] + h3ls[task * 5 + 3] + h3ls[task * 5 + 4];
      hm[task] = a / 5.f;
    }
  }
  __syncthreads();
  {
    int m0 = hh ? 3 : 0, mc = hh ? 2 : 3;
    const float* wrow = Ws1fg + o * 64;
    for (int mi = 0; mi < mc; ++mi) {
      int m = m0 + mi;
      float p[3] = {0, 0, 0};
      for (int c = 0; c < 32; ++c) {
        float w = wrow[c];
        p[0] += w * h3ls[c * 15 + m]; p[1] += w * h3ls[c * 15 + 5 + m]; p[2] += w * h3ls[c * 15 + 10 + m];
      }
      for (int c = 0; c < 32; ++c) {
        float w = wrow[32 + c];
        p[0] += w * hm[c * 3 + 0]; p[1] += w * hm[c * 3 + 1]; p[2] += w * hm[c * 3 + 2];
      }
      float nrm = sqrtf(p[0] * p[0] + p[1] * p[1] + p[2] * p[2]) + 1e-6f;
      accS += nrm; accQ += (double)nrm * (double)nrm;
    }
  }
  double oS = accS + __shfl_down(accS, 1, 64);
  double oQ = accQ + __shfl_down(accQ, 1, 64);
  if (hh == 0) {
    part[((size_t)s * 32 + o) * 2 + 0] = oS;
    part[((size_t)s * 32 + o) * 2 + 1] = oQ;
  }
}

__global__ __launch_bounds__(64) void k_s1_pass2(const float* H3,
    const float* Ws1fg, const float* Ws1dg, const float* gs1, const float* bs1, const float* st4,
    const float* Ws2fg, float* Z1, float* part5)
{
  __shared__ __align__(16) float h3ls[480];
  __shared__ float hm[96], z1ls[480];
  __shared__ float gls[32], bls[32], stls[64];
  int l = threadIdx.x;
  if (l < 32) { gls[l] = gs1[l]; bls[l] = bs1[l]; }
  if (l < 64) stls[l] = st4[l];
  int o = l >> 1, hh = l & 1;
  double accS = 0, accQ = 0;
  int s = blockIdx.x;
  __syncthreads();
  {
    const float4* src = (const float4*)(H3 + (size_t)s * 480);
    float4* dst = (float4*)h3ls;
    for (int r = l; r < 120; r += 64) dst[r] = src[r];
  }
  __syncthreads();
  for (int t = 0; t < 2; ++t) {
    int task = t * 64 + l;
    if (task < 96) {
      float a = h3ls[task * 5 + 0] + h3ls[task * 5 + 1] + h3ls[task * 5 + 2] + h3ls[task * 5 + 3] + h3ls[task * 5 + 4];
      hm[task] = a / 5.f;
    }
  }
  __syncthreads();
  {
    int m0 = hh ? 3 : 0, mc = hh ? 2 : 3;
    float mean = stls[o * 2], rstd = stls[o * 2 + 1], gg = gls[o], bb = bls[o];
    const float* wfrow = Ws1fg + o * 64;
    const float* wdrow = Ws1dg + o * 64;
    for (int mi = 0; mi < mc; ++mi) {
      int m = m0 + mi;
      float p[3] = {0, 0, 0}, dd[3] = {0, 0, 0};
      for (int c = 0; c < 32; ++c) {
        float wA = wfrow[c], wB = wdrow[c];
        float v0 = h3ls[c * 15 + m], v1 = h3ls[c * 15 + 5 + m], v2 = h3ls[c * 15 + 10 + m];
        p[0] += wA * v0; p[1] += wA * v1; p[2] += wA * v2;
        dd[0] += wB * v0; dd[1] += wB * v1; dd[2] += wB * v2;
      }
      for (int c = 0; c < 32; ++c) {
        float wA = wfrow[32 + c], wB = wdrow[32 + c];
        float v0 = hm[c * 3 + 0], v1 = hm[c * 3 + 1], v2 = hm[c * 3 + 2];
        p[0] += wA * v0; p[1] += wA * v1; p[2] += wA * v2;
        dd[0] += wB * v0; dd[1] += wB * v1; dd[2] += wB * v2;
      }
      float nrm = sqrtf(p[0] * p[0] + p[1] * p[1] + p[2] * p[2]) + 1e-6f;
      float outv[3];
      lrelu3(p, dd, nrm, mean, rstd, gg, bb, outv);
      z1ls[o * 15 + m] = outv[0];
      z1ls[o * 15 + 5 + m] = outv[1];
      z1ls[o * 15 + 10 + m] = outv[2];
      Z1[(size_t)s * 480 + o * 15 + m] = outv[0];
      Z1[(size_t)s * 480 + o * 15 + 5 + m] = outv[1];
      Z1[(size_t)s * 480 + o * 15 + 10 + m] = outv[2];
    }
  }
  __syncthreads();
  if (l < 32) {
    int m0 = hh ? 3 : 0, mc = hh ? 2 : 3;
    const float* wrow = Ws2fg + o * 32;
    for (int mi = 0; mi < mc; ++mi) {
      int m = m0 + mi;
      float p[3] = {0, 0, 0};
      for (int c = 0; c < 32; ++c) {
        float w = wrow[c];
        p[0] += w * z1ls[c * 15 + m]; p[1] += w * z1ls[c * 15 + 5 + m]; p[2] += w * z1ls[c * 15 + 10 + m];
      }
      float nrm = sqrtf(p[0] * p[0] + p[1] * p[1] + p[2] * p[2]) + 1e-6f;
      accS += nrm; accQ += (double)nrm * (double)nrm;
    }
  }
  double oS = accS + __shfl_down(accS, 1, 64);
  double oQ = accQ + __shfl_down(accQ, 1, 64);
  if (hh == 0 && l < 32) {
    part5[((size_t)s * 16 + o) * 2 + 0] = (float)oS;
    part5[((size_t)s * 16 + o) * 2 + 1] = (float)oQ;
  }
}

__global__ __launch_bounds__(64) void k_final(const float* Z1, const float* H3,
    const float* X1, const float* X2,
    const float* Ws2fg, const float* Ws2dg, const float* gs2, const float* bs2, const float* st5,
    const float* Wsling, const float* Wh1g, const float* bh1g, const float* Wh2g, const float* Wp3g,
    const float* scn, const float* rotn,
    float* out_hs, float* out_ks, float* ENT)
{
  __shared__ __align__(16) float z1ls[480];
  __shared__ __align__(16) float h3ls[480];
  __shared__ __align__(16) float x1ls[480];
  __shared__ __align__(16) float x2ls[480];
  __shared__ float hm[96];
  __shared__ float z2ls[240], z0ls[45], xmaxls[192];
  __shared__ __align__(16) float phsp[320];   // aliased as double ddot[160] after phsls
  __shared__ __align__(16) float xmp[64];     // aliased as double pkd[9] after phsls
  __shared__ float pooled[96], phsls[5];
  __shared__ float mat[25], mat2[25], scls[5], ssls[5];
  __shared__ int ordls[5];
  __shared__ float gls[16], bls[16], stls[32];
  double* ddot = (double*)phsp;   // 320 floats = 160 doubles
  double* pkd  = (double*)xmp;    // 64 floats  >= 9 doubles
  int l = threadIdx.x;
  if (l < 16) { gls[l] = gs2[l]; bls[l] = bs2[l]; }
  if (l < 32) stls[l] = st5[l];
  float bh1v = bh1g[0];
  int o = l >> 1, hh = l & 1;
  int s = blockIdx.x;
  __syncthreads();
  {
    const float4* sz = (const float4*)(Z1 + (size_t)s * 480);
    const float4* sh = (const float4*)(H3 + (size_t)s * 480);
    const float4* s1 = (const float4*)(X1 + (size_t)s * 480);
    const float4* s2 = (const float4*)(X2 + (size_t)s * 480);
    float4* dz = (float4*)z1ls; float4* dh = (float4*)h3ls;
    float4* d1 = (float4*)x1ls; float4* d2 = (float4*)x2ls;
    for (int r = l; r < 120; r += 64) { dz[r] = sz[r]; dh[r] = sh[r]; d1[r] = s1[r]; d2[r] = s2[r]; }
  }
  __syncthreads();
  if (l < 32) {
    int m0 = hh ? 3 : 0, mc = hh ? 2 : 3;
    float mean = stls[o * 2], rstd = stls[o * 2 + 1], gg = gls[o], bb = bls[o];
    const float* wfrow = Ws2fg + o * 32;
    const float* wdrow = Ws2dg + o * 32;
    for (int mi = 0; mi < mc; ++mi) {
      int m = m0 + mi;
      float p[3] = {0, 0, 0}, dd[3] = {0, 0, 0};
      for (int c = 0; c < 32; ++c) {
        float wA = wfrow[c], wB = wdrow[c];
        float v0 = z1ls[c * 15 + m], v1 = z1ls[c * 15 + 5 + m], v2 = z1ls[c * 15 + 10 + m];
        p[0] += wA * v0; p[1] += wA * v1; p[2] += wA * v2;
        dd[0] += wB * v0; dd[1] += wB * v1; dd[2] += wB * v2;
      }
      float nrm = sqrtf(p[0] * p[0] + p[1] * p[1] + p[2] * p[2]) + 1e-6f;
      float outv[3];
      lrelu3(p, dd, nrm, mean, rstd, gg, bb, outv);
      z2ls[o * 15 + m] = outv[0];
      z2ls[o * 15 + 5 + m] = outv[1];
      z2ls[o * 15 + 10 + m] = outv[2];
    }
  }
  for (int t = 0; t < 2; ++t) {
    int task = t * 64 + l;
    if (task < 96) {
      float a = h3ls[task * 5 + 0] + h3ls[task * 5 + 1] + h3ls[task * 5 + 2] + h3ls[task * 5 + 3] + h3ls[task * 5 + 4];
      hm[task] = a / 5.f;
    }
  }
  __syncthreads();
  if (l < 45) {
    int j = l / 15, kk = (l / 5) % 3, m = l % 5;
    float a = 0.f;
    for (int c = 0; c < 16; ++c) a += Wsling[j * 16 + c] * z2ls[c * 15 + kk * 5 + m];
    z0ls[l] = a;
  }
  __syncthreads();
  for (int t = 0; t < 3; ++t) {
    int r = t * 64 + l;
    if (r < 192) {
      int i = r / 3, kk = r % 3;
      float vmax = -3.4e38f;
      for (int m = 0; m < 5; ++m) {
        float v = 0.f;
        #pragma unroll
        for (int j = 0; j < 3; ++j) {
          float hv = (i < 32) ? h3ls[i * 15 + j * 5 + m] : hm[(i - 32) * 3 + j];
          v += hv * z0ls[(j * 3 + kk) * 5 + m];
        }
        vmax = fmaxf(vmax, v);
      }
      xmaxls[r] = vmax;
    }
  }
  __syncthreads();
  {
    float xmacc = 0.f;
    float pacc[5] = {0, 0, 0, 0, 0};
    for (int rr = l; rr < 192; rr += 64) {
      xmacc += Wh1g[rr] * xmaxls[rr];
      int i = rr / 3, kk = rr % 3;
      float w = Wh1g[192 + rr];
      for (int m = 0; m < 5; ++m) {
        float v = 0.f;
        #pragma unroll
        for (int j = 0; j < 3; ++j) {
          float xv = (i < 32) ? x1ls[i * 15 + j * 5 + m] : x2ls[(i - 32) * 15 + j * 5 + m];
          v += xv * z0ls[(j * 3 + kk) * 5 + m];
        }
        pacc[m] += w * v;
      }
    }
    xmp[l] = xmacc;
    #pragma unroll
    for (int m = 0; m < 5; ++m) phsp[m * 64 + l] = pacc[m];
  }
  __syncthreads();
  if (l < 5) {
    float xs = 0.f;
    for (int k2 = 0; k2 < 64; ++k2) xs += xmp[k2];
    float a = 0.f;
    for (int k2 = 0; k2 < 64; ++k2) a += phsp[l * 64 + k2];
    phsls[l] = xs + a + bh1v;
  }
  __syncthreads();   // phsp/xmp lifetime ends; ddot/pkd aliases begin
  // pooled dots in double: 3 independent accumulators per task (ILP),
  // per-j c2-ascending order identical to reference.
  for (int t = 0; t < 3; ++t) {
    int task = t * 64 + l;
    if (task < 160) {
      int cc = task & 31, m = task >> 5;
      const float* wrow = Wp3g + cc * 32;
      double accj[3] = {0.0, 0.0, 0.0};
      for (int c2 = 0; c2 < 32; ++c2) {
        double w = (double)wrow[c2];
        #pragma unroll
        for (int j = 0; j < 3; ++j)
          accj[j] += w * (double)x1ls[c2 * 15 + j * 5 + m];
      }
      double acc = 0.0;
      #pragma unroll
      for (int j = 0; j < 3; ++j)
        acc += (double)x1ls[cc * 15 + j * 5 + m] * accj[j];
      ddot[cc * 5 + m] = acc;
    }
  }
  __syncthreads();
  if (l < 32) {
    double best = -1e300; int bi = 0;
    for (int m = 0; m < 5; ++m) { double v = ddot[l * 5 + m]; if (v > best) { best = v; bi = m; } }
    pooled[l * 3 + 0] = x1ls[l * 15 + bi];
    pooled[l * 3 + 1] = x1ls[l * 15 + 5 + bi];
    pooled[l * 3 + 2] = x1ls[l * 15 + 10 + bi];
  }
  __syncthreads();
  if (l < 9) {
    int o2 = l / 3, i = l % 3;
    double a = 0.0;
    for (int c = 0; c < 32; ++c) a += (double)Wh2g[o2 * 32 + c] * (double)pooled[c * 3 + i];
    pkd[i * 3 + o2] = a;
  }
  if (l < 5) scls[l] = phsls[l] + scn[(size_t)s * 5 + l];
  __syncthreads();
  if (l < 5) {
    float nr = sqrtf(scls[0] * scls[0] + scls[1] * scls[1] + scls[2] * scls[2] + scls[3] * scls[3] + scls[4] * scls[4]);
    float v = scls[l] / fmaxf(nr, 1e-12f);
    __syncthreads();
    scls[l] = v;
  } else { __syncthreads(); }
  __syncthreads();
  if (l == 0) {
    unsigned chosen = 0u;
    for (int r = 0; r < 5; ++r) {
      float best = -3.4e38f; int bi = 0;
      for (int n = 0; n < 5; ++n) {
        if ((chosen >> n) & 1u) continue;
        if (scls[n] > best) { best = scls[n]; bi = n; }
      }
      ordls[r] = bi; ssls[r] = best; chosen |= (1u << bi);
    }
  }
  __syncthreads();
  float lp = 0.f;
  if (l < 25) {
    int i = l / 5, j = l % 5;
    lp = -fabsf(scls[i] - ssls[j]) / 0.01f;
  }
  for (int itn = 0; itn < 20; ++itn) {
    if (l < 25) mat[l] = lp;
    __syncthreads();
    if (l < 25) {
      int i = l / 5;
      float m0 = mat[i * 5], m1 = mat[i * 5 + 1], m2 = mat[i * 5 + 2], m3 = mat[i * 5 + 3], m4 = mat[i * 5 + 4];
      float mx = fmaxf(fmaxf(fmaxf(m0, m1), fmaxf(m2, m3)), m4);
      float ssum = __expf(m0 - mx) + __expf(m1 - mx) + __expf(m2 - mx) + __expf(m3 - mx) + __expf(m4 - mx);
      lp -= (mx + __logf(ssum));
    }
    __syncthreads();
    if (l < 25) mat[l] = lp;
    __syncthreads();
    if (l < 25) {
      int j = l % 5;
      float m0 = mat[j], m1 = mat[5 + j], m2 = mat[10 + j], m3 = mat[15 + j], m4 = mat[20 + j];
      float mx = fmaxf(fmaxf(fmaxf(m0, m1), fmaxf(m2, m3)), m4);
      float ssum = __expf(m0 - mx) + __expf(m1 - mx) + __expf(m2 - mx) + __expf(m3 - mx) + __expf(m4 - mx);
      lp -= (mx + __logf(ssum));
    }
    __syncthreads();
  }
  float soft = 0.f;
  if (l < 25) {
    int i = l / 5, j = l % 5;
    soft = __expf(lp);
    float hard = (ordls[j] == i) ? 1.f : 0.f;
    out_hs[(size_t)s * 25 + l] = (hard - soft) + soft;
    mat[l] = fmaxf(soft, 1e-12f);
  }
  __syncthreads();
  if (l < 25) {
    int i = l / 5, j = l % 5;
    float scl = mat[l];
    float colsum = mat[j] + mat[5 + j] + mat[10 + j] + mat[15 + j] + mat[20 + j];
    float rowsum = mat[i * 5] + mat[i * 5 + 1] + mat[i * 5 + 2] + mat[i * 5 + 3] + mat[i * 5 + 4];
    float pc = scl / fmaxf(colsum, 1e-12f);
    float pr = scl / fmaxf(rowsum, 1e-12f);
    float t2 = -pc * fmaxf(__logf(pc), -100.f);
    float t3 = -pr * fmaxf(__logf(pr), -100.f);
    mat2[l] = t2 + t3;
  }
  __syncthreads();
  if (l == 0) {
    float a = 0.f;
    for (int k2 = 0; k2 < 25; ++k2) a += mat2[k2];
    ENT[s] = a;
    double M[9];
    #pragma unroll
    for (int r = 0; r < 9; ++r) M[r] = pkd[r] + (double)rotn[(size_t)s * 9 + r];
    double a0 = M[0], a1 = M[3], a2 = M[6];
    double n0 = sqrt(a0 * a0 + a1 * a1 + a2 * a2) + 1e-12;
    double e10 = a0 / n0, e11 = a1 / n0, e12 = a2 / n0;
    double b0 = M[1], b1 = M[4], b2 = M[7];
    double t1 = e10 * b0 + e11 * b1 + e12 * b2;
    double v20 = b0 - t1 * e10, v21 = b1 - t1 * e11, v22 = b2 - t1 * e12;
    double n2 = sqrt(v20 * v20 + v21 * v21 + v22 * v22) + 1e-12;
    double e20 = v20 / n2, e21 = v21 / n2, e22 = v22 / n2;
    double c0 = M[2], c1 = M[5], c2 = M[8];
    double ta = e10 * c0 + e11 * c1 + e12 * c2;
    double tb = e20 * c0 + e21 * c1 + e22 * c2;
    double v30 = c0 - ta * e10 - tb * e20, v31 = c1 - ta * e11 - tb * e21, v32 = c2 - ta * e12 - tb * e22;
    double n3 = sqrt(v30 * v30 + v31 * v31 + v32 * v32) + 1e-12;
    double e30 = v30 / n3, e31 = v31 / n3, e32 = v32 / n3;
    float* dst = out_ks + (size_t)s * 9;
    dst[0] = (float)e10; dst[1] = (float)e20; dst[2] = (float)e30;
    dst[3] = (float)e11; dst[4] = (float)e21; dst[5] = (float)e31;
    dst[6] = (float)e12; dst[7] = (float)e22; dst[8] = (float)e32;
  }
}

__global__ __launch_bounds__(256) void k_ent_red(const float* ENT, float* outp)
{
  __shared__ double red[256];
  int t = threadIdx.x;
  double a = 0;
  for (int i = t; i < 8192; i += 256) a += (double)ENT[i];
  red[t] = a;
  __syncthreads();
  if (t == 0) {
    double sum = 0;
    for (int k = 0; k < 256; ++k) sum += red[k];
    outp[0] = (float)(sum / 40960.0);
  }
}

// ---------------------------------------------------------------- launch

extern "C" void kernel_launch(void* const* d_in, const int* in_sizes, int n_in,
                              void* d_out, int out_size, void* d_ws, size_t ws_size,
                              hipStream_t stream)
{
  (void)in_sizes; (void)n_in; (void)out_size;
  const float* nf    = (const float*)d_in[0];
  const float* noise = (const float*)d_in[1];
  const float* scn   = (const float*)d_in[2];
  const float* rotn  = (const float*)d_in[3];
  const float* Wf1 = (const float*)d_in[4],  *Wd1 = (const float*)d_in[5];
  const float* g1  = (const float*)d_in[6],  *b1  = (const float*)d_in[7];
  const float* Wf2 = (const float*)d_in[8],  *Wd2 = (const float*)d_in[9];
  const float* g2  = (const float*)d_in[10], *b2  = (const float*)d_in[11];
  const float* Wf3 = (const float*)d_in[12], *Wd3 = (const float*)d_in[13];
  const float* g3  = (const float*)d_in[14], *b3  = (const float*)d_in[15];
  const float* Wp1 = (const float*)d_in[16], *Wp2 = (const float*)d_in[17], *Wp3 = (const float*)d_in[18];
  const float* Ws1f = (const float*)d_in[19], *Ws1d = (const float*)d_in[20];
  const float* gs1  = (const float*)d_in[21], *bs1  = (const float*)d_in[22];
  const float* Ws2f = (const float*)d_in[23], *Ws2d = (const float*)d_in[24];
  const float* gs2  = (const float*)d_in[25], *bs2  = (const float*)d_in[26];
  const float* Wslin = (const float*)d_in[27];
  const float* Wh1   = (const float*)d_in[28];
  const float* bh1   = (const float*)d_in[29];
  const float* Wh2   = (const float*)d_in[30];

  // workspace layout (total 63,997,184 B):
  //   X1, X2, H3, Z1 : 4 x 15,728,640 B
  //   ENT            : 32,768 B   (doubles as RED1 scratch)
  //   ST             : 1,280 B
  //   legacy slot    : 1,048,576 B (PART5 float pairs)
  // PART_main (4 MB doubles) aliases the head of Z1 (dead until k_s1_pass2).
  const size_t SZ = (size_t)8192 * 480;
  if (ws_size < 63997184ull) return;
  float* ws  = (float*)d_ws;
  float* X1  = ws;
  float* X2  = X1 + SZ;
  float* H3  = X2 + SZ;
  float* Z1  = H3 + SZ;
  float* ENT = Z1 + SZ;
  float* ST  = ENT + 8192;
  float* PART5 = ST + 320;
  double* PARTm = (double*)Z1;
  double* RED1  = (double*)ENT;
  float* st1 = ST, *st2 = ST + 64, *st3 = ST + 128, *st4 = ST + 192, *st5 = ST + 256;

  float* out_hs = (float*)d_out;
  float* out_ks = out_hs + 204800;
  float* out_sc = out_hs + 278528;

  dim3 grid(NSAMP), blk(64);
  k_l1_pass1<<<grid, blk, 0, stream>>>(nf, noise, Wf1, PARTm);
  k_red1<<<64, 64, 0, stream>>>(PARTm, RED1, 32);
  k_red2<<<1, 64, 0, stream>>>(RED1, st1, 32, 163840.f);
  k_l1_pass2<<<grid, blk, 0, stream>>>(nf, noise, Wf1, Wd1, g1, b1, st1, Wp1, Wf2, X1, PARTm);
  k_red1<<<64, 64, 0, stream>>>(PARTm, RED1, 32);
  k_red2<<<1, 64, 0, stream>>>(RED1, st2, 32, 163840.f);
  k_l2_pass2<<<grid, blk, 0, stream>>>(X1, Wf2, Wd2, g2, b2, st2, Wp2, Wf3, X2, PARTm);
  k_red1<<<64, 64, 0, stream>>>(PARTm, RED1, 32);
  k_red2<<<1, 64, 0, stream>>>(RED1, st3, 32, 40960.f);
  k_l3_pass2<<<grid, blk, 0, stream>>>(X1, X2, Wf3, Wd3, g3, b3, st3, Ws1f, H3, PARTm);
  k_red1<<<64, 64, 0, stream>>>(PARTm, RED1, 32);
  k_red2<<<1, 64, 0, stream>>>(RED1, st4, 32, 40960.f);
  k_s1_pass2<<<grid, blk, 0, stream>>>(H3, Ws1f, Ws1d, gs1, bs1, st4, Ws2f, Z1, PART5);
  k_red1f<<<64, 64, 0, stream>>>(PART5, RED1, 16);
  k_red2<<<1, 64, 0, stream>>>(RED1, st5, 16, 40960.f);
  k_final<<<grid, blk, 0, stream>>>(Z1, H3, X1, X2, Ws2f, Ws2d, gs2, bs2, st5,
                                    Wslin, Wh1, bh1, Wh2, Wp3, scn, rotn,
                                    out_hs, out_ks, ENT);
  k_ent_red<<<1, 256, 0, stream>>>(ENT, out_sc);
}

// Round 12
// 531.098 us; speedup vs baseline: 1.7826x; 1.1501x over previous
//
#include <hip/hip_runtime.h>
#include <math.h>

#define NSAMP 8192   // one block per sample

// LDS padding strides
#define WS4  5    // [32][4] weights
#define HS   20   // h1/h2 row stride: 16B-aligned quads for ds_read_b128 maxpool reads

// ---------------------------------------------------------------- helpers

__device__ __forceinline__ void knn_compute(const float* xls, int C3, float* dls, int* idxls, int l)
{
  if (l < 25) {
    int m = l / 5, n = l % 5;
    float acc = 0.f;
    for (int r = 0; r < C3; ++r) acc += xls[r * 5 + m] * xls[r * 5 + n];
    dls[l] = acc;  // inner
  }
  __syncthreads();
  float dm = 0.f, dn = 0.f, inn = 0.f;
  if (l < 25) { int m = l / 5, n = l % 5; dm = dls[m * 5 + m]; dn = dls[n * 5 + n]; inn = dls[l]; }
  __syncthreads();
  if (l < 25) dls[l] = 2.f * inn - dm - dn;
  __syncthreads();
  if (l < 5) {
    int m = l; unsigned chosen = 0u;
    for (int kk = 0; kk < 4; ++kk) {
      float best = -3.4e38f; int bi = 0;
      for (int n = 0; n < 5; ++n) {
        if ((chosen >> n) & 1u) continue;
        float v = dls[m * 5 + n];
        if (v > best) { best = v; bi = n; }
      }
      idxls[m * 4 + kk] = bi;
      chosen |= (1u << bi);
    }
  }
  __syncthreads();
}

template<bool WD>
__device__ __forceinline__ void feat_pd2(const float* xls, const int* idxls,
    const float* Wf, const float* Wd, int o, int m, int kk, float* p, float* d)
{
  const int nb = idxls[m * 4 + kk];
  const float* wf = Wf + o * WS4;
  const float* wd = WD ? (Wd + o * WS4) : wf;
  for (int c = 0; c < 2; ++c) {
    float wfc = wf[c];
    float wdc = WD ? wd[c] : 0.f;
    #pragma unroll
    for (int j = 0; j < 3; ++j) {
      float v = xls[c * 15 + j * 5 + nb] - xls[c * 15 + j * 5 + m];
      p[j] += wfc * v;
      if (WD) d[j] += wdc * v;
    }
  }
  for (int c = 0; c < 2; ++c) {
    float wfc = wf[2 + c];
    float wdc = WD ? wd[2 + c] : 0.f;
    #pragma unroll
    for (int j = 0; j < 3; ++j) {
      float v = xls[c * 15 + j * 5 + m];
      p[j] += wfc * v;
      if (WD) d[j] += wdc * v;
    }
  }
}

__device__ __forceinline__ void lrelu3(const float* p, const float* d, float nrm,
    float mean, float rstd, float g, float b, float* out)
{
  float nbn = g * (nrm - mean) * rstd + b;
  float s = nbn / nrm;
  float pb0 = p[0] * s, pb1 = p[1] * s, pb2 = p[2] * s;
  float dot = pb0 * d[0] + pb1 * d[1] + pb2 * d[2];
  if (dot >= 0.f) { out[0] = pb0; out[1] = pb1; out[2] = pb2; }
  else {
    float dsq = d[0] * d[0] + d[1] * d[1] + d[2] * d[2];
    float f = 0.8f * (dot / (dsq + 1e-6f));
    out[0] = pb0 - f * d[0]; out[1] = pb1 - f * d[1]; out[2] = pb2 - f * d[2];
  }
}

__device__ __forceinline__ void load_x_sample(const float* nf, const float* noise, int s, int l, float* xls)
{
  if (l < 30) {
    int c = l / 15, j = (l / 5) % 3, m = l % 5, b = s >> 6;
    xls[l] = nf[((b * 5 + m) * 3 + j) * 2 + c] + noise[(((size_t)s * 5 + m) * 3 + j) * 2 + c];
  }
}

// maxpool with 12 independent accumulators, quad LDS reads (bit-identical order:
// dv[kk][j] sums c ascending; final dot sums j ascending; first-wins argmax).
__device__ __forceinline__ void maxpool_task(const float* Wg, const float* H,
    int oo, int m, int* bi_out)
{
  const float* wrow = Wg + oo * 32;
  float acc[4][3];
  #pragma unroll
  for (int kk = 0; kk < 4; ++kk)
    #pragma unroll
    for (int j = 0; j < 3; ++j) acc[kk][j] = 0.f;
  for (int c = 0; c < 32; ++c) {
    float w = wrow[c];
    #pragma unroll
    for (int j = 0; j < 3; ++j) {
      const float4 hv = *(const float4*)(H + (c * 3 + j) * HS + m * 4);  // 16B-aligned (HS=20)
      acc[0][j] += w * hv.x;
      acc[1][j] += w * hv.y;
      acc[2][j] += w * hv.z;
      acc[3][j] += w * hv.w;
    }
  }
  float best = -3.4e38f; int bi = 0;
  #pragma unroll
  for (int kk = 0; kk < 4; ++kk) {
    float a2 = 0.f;
    #pragma unroll
    for (int j = 0; j < 3; ++j) a2 += H[(oo * 3 + j) * HS + m * 4 + kk] * acc[kk][j];
    if (a2 > best) { best = a2; bi = kk; }
  }
  *bi_out = bi;
}

// ---------------------------------------------------------------- kernels

__global__ __launch_bounds__(64) void k_l1_pass1(const float* nf, const float* noise,
    const float* Wf1, double* part)
{
  __shared__ float xls[30], dls[25], wf[32 * WS4];
  __shared__ int idxls[20];
  int l = threadIdx.x;
  for (int r = l; r < 128; r += 64) wf[(r >> 2) * WS4 + (r & 3)] = Wf1[r];
  int o = l >> 1, hh = l & 1;
  double accS = 0, accQ = 0;
  int s = blockIdx.x;
  __syncthreads();
  load_x_sample(nf, noise, s, l, xls);
  __syncthreads();
  knn_compute(xls, 6, dls, idxls, l);
  for (int t = 0; t < 10; ++t) {
    int e = hh * 10 + t; int m = e >> 2, kk = e & 3;
    float p[3] = {0, 0, 0}, dum[3];
    feat_pd2<false>(xls, idxls, wf, wf, o, m, kk, p, dum);
    float nrm = sqrtf(p[0] * p[0] + p[1] * p[1] + p[2] * p[2]) + 1e-6f;
    accS += nrm; accQ += (double)nrm * (double)nrm;
  }
  double oS = accS + __shfl_down(accS, 1, 64);
  double oQ = accQ + __shfl_down(accQ, 1, 64);
  if (hh == 0) {
    part[((size_t)s * 32 + o) * 2 + 0] = oS;
    part[((size_t)s * 32 + o) * 2 + 1] = oQ;
  }
}

// two-stage deterministic reduce
__global__ __launch_bounds__(64) void k_red1(const double* part, double* red1, int C)
{
  int p = threadIdx.x, b = blockIdx.x;
  double acc = 0;
  if (p < 2 * C) {
    int o = p >> 1, q = p & 1;
    for (int g = b * 128; g < (b + 1) * 128; ++g)
      acc += part[((size_t)g * C + o) * 2 + q];
  }
  red1[b * 64 + p] = acc;
}

__global__ __launch_bounds__(64) void k_red1f(const float* part, double* red1, int C)
{
  int p = threadIdx.x, b = blockIdx.x;
  double acc = 0;
  if (p < 2 * C) {
    int o = p >> 1, q = p & 1;
    for (int g = b * 128; g < (b + 1) * 128; ++g)
      acc += (double)part[((size_t)g * C + o) * 2 + q];
  }
  red1[b * 64 + p] = acc;
}

__global__ __launch_bounds__(64) void k_red2(const double* red1, float* stats, int C, float count)
{
  __shared__ double tot[64];
  int p = threadIdx.x;
  double a = 0;
  if (p < 2 * C) for (int b = 0; b < 64; ++b) a += red1[b * 64 + p];
  tot[p] = a;
  __syncthreads();
  if (p < C) {
    double sum = tot[p * 2 + 0], ssq = tot[p * 2 + 1];
    double mean = sum / (double)count;
    double var = ssq / (double)count - mean * mean;
    stats[p * 2 + 0] = (float)mean;
    stats[p * 2 + 1] = (float)(1.0 / sqrt(var + 1e-5));
  }
}

// layer1 pass2 (h1, maxpool->x1) + layer2 pass1 stats via A/B factorization
__global__ __launch_bounds__(64) void k_l1_pass2(const float* nf, const float* noise,
    const float* Wf1g, const float* Wd1g, const float* g1, const float* b1, const float* st1,
    const float* Wp1g, const float* Wf2g, float* X1, double* part)
{
  __shared__ float xls[30], dls[25];
  __shared__ __align__(16) float h1[96 * HS];
  __shared__ __align__(16) float x1ls[480];
  __shared__ float wf1[32 * WS4], wd1[32 * WS4];
  __shared__ float AB2[960];
  __shared__ float gls[32], bls[32], stls[64];
  __shared__ int idxls[20], idx2[20];
  int l = threadIdx.x;
  for (int r = l; r < 128; r += 64) { int q = (r >> 2) * WS4 + (r & 3); wf1[q] = Wf1g[r]; wd1[q] = Wd1g[r]; }
  if (l < 32) { gls[l] = g1[l]; bls[l] = b1[l]; }
  if (l < 64) stls[l] = st1[l];
  int o = l >> 1, hh = l & 1;
  double accS = 0, accQ = 0;
  int s = blockIdx.x;
  __syncthreads();
  load_x_sample(nf, noise, s, l, xls);
  __syncthreads();
  knn_compute(xls, 6, dls, idxls, l);
  {
    float mean = stls[o * 2], rstd = stls[o * 2 + 1], gg = gls[o], bb = bls[o];
    for (int t = 0; t < 10; ++t) {
      int e = hh * 10 + t; int m = e >> 2, kk = e & 3;
      float p[3] = {0, 0, 0}, dd[3] = {0, 0, 0};
      feat_pd2<true>(xls, idxls, wf1, wd1, o, m, kk, p, dd);
      float nrm = sqrtf(p[0] * p[0] + p[1] * p[1] + p[2] * p[2]) + 1e-6f;
      float outv[3];
      lrelu3(p, dd, nrm, mean, rstd, gg, bb, outv);
      h1[(o * 3 + 0) * HS + m * 4 + kk] = outv[0];
      h1[(o * 3 + 1) * HS + m * 4 + kk] = outv[1];
      h1[(o * 3 + 2) * HS + m * 4 + kk] = outv[2];
    }
  }
  __syncthreads();
  for (int t = 0; t < 3; ++t) {
    int task = t * 64 + l;
    if (task < 160) {
      int oo = task & 31, m = task >> 5;
      int bi;
      maxpool_task(Wp1g, h1, oo, m, &bi);
      for (int j = 0; j < 3; ++j) {
        float v = h1[(oo * 3 + j) * HS + m * 4 + bi];
        x1ls[(oo * 3 + j) * 5 + m] = v;
        X1[(size_t)s * 480 + (oo * 3 + j) * 5 + m] = v;
      }
    }
  }
  __syncthreads();
  knn_compute(x1ls, 96, dls, idx2, l);
  {
    float acc[15];
    #pragma unroll
    for (int r = 0; r < 15; ++r) acc[r] = 0.f;
    const float* wrow = Wf2g + o * 64 + hh * 32;
    for (int c = 0; c < 32; ++c) {
      float wc = wrow[c];
      #pragma unroll
      for (int r = 0; r < 15; ++r) acc[r] += wc * x1ls[c * 15 + r];
    }
    #pragma unroll
    for (int r = 0; r < 15; ++r) AB2[hh * 480 + o * 15 + r] = acc[r];
  }
  __syncthreads();
  {
    const float* A2 = AB2 + o * 15;
    const float* B2 = AB2 + 480 + o * 15;
    for (int t = 0; t < 10; ++t) {
      int e = hh * 10 + t; int m = e >> 2, kk = e & 3;
      int nb = idx2[m * 4 + kk];
      float p0 = A2[nb] - A2[m] + B2[m];
      float p1 = A2[5 + nb] - A2[5 + m] + B2[5 + m];
      float p2 = A2[10 + nb] - A2[10 + m] + B2[10 + m];
      float nrm = sqrtf(p0 * p0 + p1 * p1 + p2 * p2) + 1e-6f;
      accS += nrm; accQ += (double)nrm * (double)nrm;
    }
  }
  double oS = accS + __shfl_down(accS, 1, 64);
  double oQ = accQ + __shfl_down(accQ, 1, 64);
  if (hh == 0) {
    part[((size_t)s * 32 + o) * 2 + 0] = oS;
    part[((size_t)s * 32 + o) * 2 + 1] = oQ;
  }
}

// layer2 pass2 via A/B factorization + maxpool + layer3 pass1 stats
__global__ __launch_bounds__(64) void k_l2_pass2(const float* X1,
    const float* Wf2g, const float* Wd2g, const float* g2, const float* b2, const float* st2,
    const float* Wp2g, const float* Wf3g, float* X2, double* part)
{
  __shared__ __align__(16) float x1ls[480];
  __shared__ __align__(16) float h2[96 * HS];
  __shared__ float dls[25], x2ls[480];
  __shared__ float ABls[1920];
  __shared__ float gls[32], bls[32], stls[64];
  __shared__ int idx2[20];
  int l = threadIdx.x;
  if (l < 32) { gls[l] = g2[l]; bls[l] = b2[l]; }
  if (l < 64) stls[l] = st2[l];
  int o = l >> 1, hh = l & 1;
  double accS = 0, accQ = 0;
  int s = blockIdx.x;
  __syncthreads();
  {
    const float4* src = (const float4*)(X1 + (size_t)s * 480);
    float4* dst = (float4*)x1ls;
    for (int r = l; r < 120; r += 64) dst[r] = src[r];
  }
  __syncthreads();
  knn_compute(x1ls, 96, dls, idx2, l);
  {
    float accF[15], accD[15];
    #pragma unroll
    for (int r = 0; r < 15; ++r) { accF[r] = 0.f; accD[r] = 0.f; }
    const float* wfrow = Wf2g + o * 64 + hh * 32;
    const float* wdrow = Wd2g + o * 64 + hh * 32;
    for (int c = 0; c < 32; ++c) {
      float wfc = wfrow[c], wdc = wdrow[c];
      #pragma unroll
      for (int r = 0; r < 15; ++r) {
        float xv = x1ls[c * 15 + r];
        accF[r] += wfc * xv;
        accD[r] += wdc * xv;
      }
    }
    #pragma unroll
    for (int r = 0; r < 15; ++r) {
      ABls[hh * 480 + o * 15 + r] = accF[r];
      ABls[960 + hh * 480 + o * 15 + r] = accD[r];
    }
  }
  __syncthreads();
  {
    float mean = stls[o * 2], rstd = stls[o * 2 + 1], gg = gls[o], bb = bls[o];
    const float* Af = ABls + o * 15;
    const float* Bf = ABls + 480 + o * 15;
    const float* Ad = ABls + 960 + o * 15;
    const float* Bd = ABls + 1440 + o * 15;
    for (int t = 0; t < 10; ++t) {
      int e = hh * 10 + t; int m = e >> 2, kk = e & 3;
      int nb = idx2[m * 4 + kk];
      float p[3], dd[3];
      #pragma unroll
      for (int j = 0; j < 3; ++j) {
        p[j]  = Af[j * 5 + nb] - Af[j * 5 + m] + Bf[j * 5 + m];
        dd[j] = Ad[j * 5 + nb] - Ad[j * 5 + m] + Bd[j * 5 + m];
      }
      float nrm = sqrtf(p[0] * p[0] + p[1] * p[1] + p[2] * p[2]) + 1e-6f;
      float outv[3];
      lrelu3(p, dd, nrm, mean, rstd, gg, bb, outv);
      h2[(o * 3 + 0) * HS + m * 4 + kk] = outv[0];
      h2[(o * 3 + 1) * HS + m * 4 + kk] = outv[1];
      h2[(o * 3 + 2) * HS + m * 4 + kk] = outv[2];
    }
  }
  __syncthreads();
  for (int t = 0; t < 3; ++t) {
    int task = t * 64 + l;
    if (task < 160) {
      int oo = task & 31, m = task >> 5;
      int bi;
      maxpool_task(Wp2g, h2, oo, m, &bi);
      for (int j = 0; j < 3; ++j) {
        float v = h2[(oo * 3 + j) * HS + m * 4 + bi];
        x2ls[(oo * 3 + j) * 5 + m] = v;
        X2[(size_t)s * 480 + (oo * 3 + j) * 5 + m] = v;
      }
    }
  }
  __syncthreads();
  {
    // layer3 pass1 stats: c-outer, per-m accumulators (weight row read once)
    int m0 = hh ? 3 : 0, mc = hh ? 2 : 3;
    float p[3][3];
    #pragma unroll
    for (int mi = 0; mi < 3; ++mi) { p[mi][0] = 0.f; p[mi][1] = 0.f; p[mi][2] = 0.f; }
    const float* wrow = Wf3g + o * 64;
    for (int c = 0; c < 64; ++c) {
      float w = wrow[c];
      const float* src = (c < 32) ? (x1ls + c * 15) : (x2ls + (c - 32) * 15);
      #pragma unroll
      for (int mi = 0; mi < 3; ++mi) {
        int m = m0 + mi; if (m > 4) m = 4;   // clamped lanes discarded below
        p[mi][0] += w * src[m]; p[mi][1] += w * src[5 + m]; p[mi][2] += w * src[10 + m];
      }
    }
    for (int mi = 0; mi < mc; ++mi) {
      float nrm = sqrtf(p[mi][0] * p[mi][0] + p[mi][1] * p[mi][1] + p[mi][2] * p[mi][2]) + 1e-6f;
      accS += nrm; accQ += (double)nrm * (double)nrm;
    }
  }
  double oS = accS + __shfl_down(accS, 1, 64);
  double oQ = accQ + __shfl_down(accQ, 1, 64);
  if (hh == 0) {
    part[((size_t)s * 32 + o) * 2 + 0] = oS;
    part[((size_t)s * 32 + o) * 2 + 1] = oQ;
  }
}

__global__ __launch_bounds__(64) void k_l3_pass2(const float* X1, const float* X2,
    const float* Wf3g, const float* Wd3g, const float* g3, const float* b3, const float* st3,
    const float* Ws1fg, float* H3, double* part)
{
  __shared__ __align__(16) float x1ls[480];
  __shared__ __align__(16) float x2ls[480];
  __shared__ float h3ls[480], hm[96], d3ls[15];
  __shared__ float wd3[64];
  __shared__ float gls[32], bls[32], stls[64];
  int l = threadIdx.x;
  if (l < 64) wd3[l] = Wd3g[l];
  if (l < 32) { gls[l] = g3[l]; bls[l] = b3[l]; }
  if (l < 64) stls[l] = st3[l];
  int o = l >> 1, hh = l & 1;
  double accS = 0, accQ = 0;
  int s = blockIdx.x;
  __syncthreads();
  {
    const float4* s1 = (const float4*)(X1 + (size_t)s * 480);
    const float4* s2 = (const float4*)(X2 + (size_t)s * 480);
    float4* d1 = (float4*)x1ls;
    float4* d2 = (float4*)x2ls;
    for (int r = l; r < 120; r += 64) { d1[r] = s1[r]; d2[r] = s2[r]; }
  }
  __syncthreads();
  if (l < 15) {
    int j = l / 5, m = l % 5;
    float a = 0.f;
    for (int c = 0; c < 64; ++c) {
      const float* src = (c < 32) ? (x1ls + c * 15) : (x2ls + (c - 32) * 15);
      a += wd3[c] * src[j * 5 + m];
    }
    d3ls[l] = a;
  }
  __syncthreads();
  {
    int m0 = hh ? 3 : 0, mc = hh ? 2 : 3;
    float mean = stls[o * 2], rstd = stls[o * 2 + 1], gg = gls[o], bb = bls[o];
    const float* wrow = Wf3g + o * 64;
    float p[3][3];
    #pragma unroll
    for (int mi = 0; mi < 3; ++mi) { p[mi][0] = 0.f; p[mi][1] = 0.f; p[mi][2] = 0.f; }
    for (int c = 0; c < 64; ++c) {
      float w = wrow[c];
      const float* src = (c < 32) ? (x1ls + c * 15) : (x2ls + (c - 32) * 15);
      #pragma unroll
      for (int mi = 0; mi < 3; ++mi) {
        int m = m0 + mi; if (m > 4) m = 4;
        p[mi][0] += w * src[m]; p[mi][1] += w * src[5 + m]; p[mi][2] += w * src[10 + m];
      }
    }
    for (int mi = 0; mi < mc; ++mi) {
      int m = m0 + mi;
      float nrm = sqrtf(p[mi][0] * p[mi][0] + p[mi][1] * p[mi][1] + p[mi][2] * p[mi][2]) + 1e-6f;
      float dd[3] = {d3ls[m], d3ls[5 + m], d3ls[10 + m]};
      float outv[3];
      lrelu3(p[mi], dd, nrm, mean, rstd, gg, bb, outv);
      h3ls[o * 15 + 0 + m] = outv[0];
      h3ls[o * 15 + 5 + m] = outv[1];
      h3ls[o * 15 + 10 + m] = outv[2];
      H3[(size_t)s * 480 + o * 15 + m] = outv[0];
      H3[(size_t)s * 480 + o * 15 + 5 + m] = outv[1];
      H3[(size_t)s * 480 + o * 15 + 10 + m] = outv[2];
    }
  }
  __syncthreads();
  for (int t = 0; t < 2; ++t) {
    int task = t * 64 + l;
    if (task < 96) {
      float a = h3ls[task * 5 + 0] + h3ls[task * 5 + 1] + h3ls[task * 5 + 2] + h3ls[task * 5 + 3] + h3ls[task * 5 + 4];
      hm[task] = a / 5.f;
    }
  }
  __syncthreads();
  {
    // s1 pass1 stats: c-outer, per-m accumulators
    int m0 = hh ? 3 : 0, mc = hh ? 2 : 3;
    const float* wrow = Ws1fg + o * 64;
    float p[3][3];
    #pragma unroll
    for (int mi = 0; mi < 3; ++mi) { p[mi][0] = 0.f; p[mi][1] = 0.f; p[mi][2] = 0.f; }
    for (int c = 0; c < 32; ++c) {
      float w = wrow[c];
      #pragma unroll
      for (int mi = 0; mi < 3; ++mi) {
        int m = m0 + mi; if (m > 4) m = 4;
        p[mi][0] += w * h3ls[c * 15 + m]; p[mi][1] += w * h3ls[c * 15 + 5 + m]; p[mi][2] += w * h3ls[c * 15 + 10 + m];
      }
    }
    for (int c = 0; c < 32; ++c) {
      float w = wrow[32 + c];
      float v0 = hm[c * 3 + 0], v1 = hm[c * 3 + 1], v2 = hm[c * 3 + 2];
      #pragma unroll
      for (int mi = 0; mi < 3; ++mi) {
        p[mi][0] += w * v0; p[mi][1] += w * v1; p[mi][2] += w * v2;
      }
    }
    for (int mi = 0; mi < mc; ++mi) {
      float nrm = sqrtf(p[mi][0] * p[mi][0] + p[mi][1] * p[mi][1] + p[mi][2] * p[mi][2]) + 1e-6f;
      accS += nrm; accQ += (double)nrm * (double)nrm;
    }
  }
  double oS = accS + __shfl_down(accS, 1, 64);
  double oQ = accQ + __shfl_down(accQ, 1, 64);
  if (hh == 0) {
    part[((size_t)s * 32 + o) * 2 + 0] = oS;
    part[((size_t)s * 32 + o) * 2 + 1] = oQ;
  }
}

__global__ __launch_bounds__(64) void k_s1_pass2(const float* H3,
    const float* Ws1fg, const float* Ws1dg, const float* gs1, const float* bs1, const float* st4,
    const float* Ws2fg, float* Z1, float* part5)
{
  __shared__ __align__(16) float h3ls[480];
  __shared__ float hm[96], z1ls[480];
  __shared__ float gls[32], bls[32], stls[64];
  int l = threadIdx.x;
  if (l < 32) { gls[l] = gs1[l]; bls[l] = bs1[l]; }
  if (l < 64) stls[l] = st4[l];
  int o = l >> 1, hh = l & 1;
  double accS = 0, accQ = 0;
  int s = blockIdx.x;
  __syncthreads();
  {
    const float4* src = (const float4*)(H3 + (size_t)s * 480);
    float4* dst = (float4*)h3ls;
    for (int r = l; r < 120; r += 64) dst[r] = src[r];
  }
  __syncthreads();
  for (int t = 0; t < 2; ++t) {
    int task = t * 64 + l;
    if (task < 96) {
      float a = h3ls[task * 5 + 0] + h3ls[task * 5 + 1] + h3ls[task * 5 + 2] + h3ls[task * 5 + 3] + h3ls[task * 5 + 4];
      hm[task] = a / 5.f;
    }
  }
  __syncthreads();
  {
    // c-outer with per-m accumulator sets for p and d (rows read once)
    int m0 = hh ? 3 : 0, mc = hh ? 2 : 3;
    float mean = stls[o * 2], rstd = stls[o * 2 + 1], gg = gls[o], bb = bls[o];
    const float* wfrow = Ws1fg + o * 64;
    const float* wdrow = Ws1dg + o * 64;
    float p[3][3], dd[3][3];
    #pragma unroll
    for (int mi = 0; mi < 3; ++mi)
      #pragma unroll
      for (int j = 0; j < 3; ++j) { p[mi][j] = 0.f; dd[mi][j] = 0.f; }
    for (int c = 0; c < 32; ++c) {
      float wA = wfrow[c], wB = wdrow[c];
      #pragma unroll
      for (int mi = 0; mi < 3; ++mi) {
        int m = m0 + mi; if (m > 4) m = 4;
        float v0 = h3ls[c * 15 + m], v1 = h3ls[c * 15 + 5 + m], v2 = h3ls[c * 15 + 10 + m];
        p[mi][0] += wA * v0; p[mi][1] += wA * v1; p[mi][2] += wA * v2;
        dd[mi][0] += wB * v0; dd[mi][1] += wB * v1; dd[mi][2] += wB * v2;
      }
    }
    for (int c = 0; c < 32; ++c) {
      float wA = wfrow[32 + c], wB = wdrow[32 + c];
      float v0 = hm[c * 3 + 0], v1 = hm[c * 3 + 1], v2 = hm[c * 3 + 2];
      #pragma unroll
      for (int mi = 0; mi < 3; ++mi) {
        p[mi][0] += wA * v0; p[mi][1] += wA * v1; p[mi][2] += wA * v2;
        dd[mi][0] += wB * v0; dd[mi][1] += wB * v1; dd[mi][2] += wB * v2;
      }
    }
    for (int mi = 0; mi < mc; ++mi) {
      int m = m0 + mi;
      float nrm = sqrtf(p[mi][0] * p[mi][0] + p[mi][1] * p[mi][1] + p[mi][2] * p[mi][2]) + 1e-6f;
      float outv[3];
      lrelu3(p[mi], dd[mi], nrm, mean, rstd, gg, bb, outv);
      z1ls[o * 15 + m] = outv[0];
      z1ls[o * 15 + 5 + m] = outv[1];
      z1ls[o * 15 + 10 + m] = outv[2];
      Z1[(size_t)s * 480 + o * 15 + m] = outv[0];
      Z1[(size_t)s * 480 + o * 15 + 5 + m] = outv[1];
      Z1[(size_t)s * 480 + o * 15 + 10 + m] = outv[2];
    }
  }
  __syncthreads();
  if (l < 32) {
    int m0 = hh ? 3 : 0, mc = hh ? 2 : 3;
    const float* wrow = Ws2fg + o * 32;
    float p[3][3];
    #pragma unroll
    for (int mi = 0; mi < 3; ++mi) { p[mi][0] = 0.f; p[mi][1] = 0.f; p[mi][2] = 0.f; }
    for (int c = 0; c < 32; ++c) {
      float w = wrow[c];
      #pragma unroll
      for (int mi = 0; mi < 3; ++mi) {
        int m = m0 + mi; if (m > 4) m = 4;
        p[mi][0] += w * z1ls[c * 15 + m]; p[mi][1] += w * z1ls[c * 15 + 5 + m]; p[mi][2] += w * z1ls[c * 15 + 10 + m];
      }
    }
    for (int mi = 0; mi < mc; ++mi) {
      float nrm = sqrtf(p[mi][0] * p[mi][0] + p[mi][1] * p[mi][1] + p[mi][2] * p[mi][2]) + 1e-6f;
      accS += nrm; accQ += (double)nrm * (double)nrm;
    }
  }
  double oS = accS + __shfl_down(accS, 1, 64);
  double oQ = accQ + __shfl_down(accQ, 1, 64);
  if (hh == 0 && l < 32) {
    part5[((size_t)s * 16 + o) * 2 + 0] = (float)oS;
    part5[((size_t)s * 16 + o) * 2 + 1] = (float)oQ;
  }
}

__global__ __launch_bounds__(64) void k_final(const float* Z1, const float* H3,
    const float* X1, const float* X2,
    const float* Ws2fg, const float* Ws2dg, const float* gs2, const float* bs2, const float* st5,
    const float* Wsling, const float* Wh1g, const float* bh1g, const float* Wh2g, const float* Wp3g,
    const float* scn, const float* rotn,
    float* out_hs, float* out_ks, float* ENT)
{
  __shared__ __align__(16) float z1ls[480];
  __shared__ __align__(16) float h3ls[480];
  __shared__ __align__(16) float x1ls[480];
  __shared__ __align__(16) float x2ls[480];
  __shared__ float hm[96];
  __shared__ float z2ls[240], z0ls[45], xmaxls[192];
  __shared__ __align__(16) float phsp[320];   // aliased as double ddot[160] after phsls
  __shared__ __align__(16) float xmp[64];     // aliased as double pkd[9] after phsls
  __shared__ float pooled[96], phsls[5];
  __shared__ float mat[25], mat2[25], scls[5], ssls[5];
  __shared__ int ordls[5];
  __shared__ float gls[16], bls[16], stls[32];
  double* ddot = (double*)phsp;
  double* pkd  = (double*)xmp;
  int l = threadIdx.x;
  if (l < 16) { gls[l] = gs2[l]; bls[l] = bs2[l]; }
  if (l < 32) stls[l] = st5[l];
  float bh1v = bh1g[0];
  int o = l >> 1, hh = l & 1;
  int s = blockIdx.x;
  __syncthreads();
  {
    const float4* sz = (const float4*)(Z1 + (size_t)s * 480);
    const float4* sh = (const float4*)(H3 + (size_t)s * 480);
    const float4* s1 = (const float4*)(X1 + (size_t)s * 480);
    const float4* s2 = (const float4*)(X2 + (size_t)s * 480);
    float4* dz = (float4*)z1ls; float4* dh = (float4*)h3ls;
    float4* d1 = (float4*)x1ls; float4* d2 = (float4*)x2ls;
    for (int r = l; r < 120; r += 64) { dz[r] = sz[r]; dh[r] = sh[r]; d1[r] = s1[r]; d2[r] = s2[r]; }
  }
  __syncthreads();
  if (l < 32) {
    int m0 = hh ? 3 : 0, mc = hh ? 2 : 3;
    float mean = stls[o * 2], rstd = stls[o * 2 + 1], gg = gls[o], bb = bls[o];
    const float* wfrow = Ws2fg + o * 32;
    const float* wdrow = Ws2dg + o * 32;
    float p[3][3], dd[3][3];
    #pragma unroll
    for (int mi = 0; mi < 3; ++mi)
      #pragma unroll
      for (int j = 0; j < 3; ++j) { p[mi][j] = 0.f; dd[mi][j] = 0.f; }
    for (int c = 0; c < 32; ++c) {
      float wA = wfrow[c], wB = wdrow[c];
      #pragma unroll
      for (int mi = 0; mi < 3; ++mi) {
        int m = m0 + mi; if (m > 4) m = 4;
        float v0 = z1ls[c * 15 + m], v1 = z1ls[c * 15 + 5 + m], v2 = z1ls[c * 15 + 10 + m];
        p[mi][0] += wA * v0; p[mi][1] += wA * v1; p[mi][2] += wA * v2;
        dd[mi][0] += wB * v0; dd[mi][1] += wB * v1; dd[mi][2] += wB * v2;
      }
    }
    for (int mi = 0; mi < mc; ++mi) {
      int m = m0 + mi;
      float nrm = sqrtf(p[mi][0] * p[mi][0] + p[mi][1] * p[mi][1] + p[mi][2] * p[mi][2]) + 1e-6f;
      float outv[3];
      lrelu3(p[mi], dd[mi], nrm, mean, rstd, gg, bb, outv);
      z2ls[o * 15 + m] = outv[0];
      z2ls[o * 15 + 5 + m] = outv[1];
      z2ls[o * 15 + 10 + m] = outv[2];
    }
  }
  for (int t = 0; t < 2; ++t) {
    int task = t * 64 + l;
    if (task < 96) {
      float a = h3ls[task * 5 + 0] + h3ls[task * 5 + 1] + h3ls[task * 5 + 2] + h3ls[task * 5 + 3] + h3ls[task * 5 + 4];
      hm[task] = a / 5.f;
    }
  }
  __syncthreads();
  if (l < 45) {
    int j = l / 15, kk = (l / 5) % 3, m = l % 5;
    float a = 0.f;
    for (int c = 0; c < 16; ++c) a += Wsling[j * 16 + c] * z2ls[c * 15 + kk * 5 + m];
    z0ls[l] = a;
  }
  __syncthreads();
  for (int t = 0; t < 3; ++t) {
    int r = t * 64 + l;
    if (r < 192) {
      int i = r / 3, kk = r % 3;
      float vmax = -3.4e38f;
      for (int m = 0; m < 5; ++m) {
        float v = 0.f;
        #pragma unroll
        for (int j = 0; j < 3; ++j) {
          float hv = (i < 32) ? h3ls[i * 15 + j * 5 + m] : hm[(i - 32) * 3 + j];
          v += hv * z0ls[(j * 3 + kk) * 5 + m];
        }
        vmax = fmaxf(vmax, v);
      }
      xmaxls[r] = vmax;
    }
  }
  __syncthreads();
  {
    float xmacc = 0.f;
    float pacc[5] = {0, 0, 0, 0, 0};
    for (int rr = l; rr < 192; rr += 64) {
      xmacc += Wh1g[rr] * xmaxls[rr];
      int i = rr / 3, kk = rr % 3;
      float w = Wh1g[192 + rr];
      for (int m = 0; m < 5; ++m) {
        float v = 0.f;
        #pragma unroll
        for (int j = 0; j < 3; ++j) {
          float xv = (i < 32) ? x1ls[i * 15 + j * 5 + m] : x2ls[(i - 32) * 15 + j * 5 + m];
          v += xv * z0ls[(j * 3 + kk) * 5 + m];
        }
        pacc[m] += w * v;
      }
    }
    xmp[l] = xmacc;
    #pragma unroll
    for (int m = 0; m < 5; ++m) phsp[m * 64 + l] = pacc[m];
  }
  __syncthreads();
  if (l < 5) {
    float xs = 0.f;
    for (int k2 = 0; k2 < 64; ++k2) xs += xmp[k2];
    float a = 0.f;
    for (int k2 = 0; k2 < 64; ++k2) a += phsp[l * 64 + k2];
    phsls[l] = xs + a + bh1v;
  }
  __syncthreads();   // phsp/xmp lifetime ends; ddot/pkd aliases begin
  for (int t = 0; t < 3; ++t) {
    int task = t * 64 + l;
    if (task < 160) {
      int cc = task & 31, m = task >> 5;
      const float* wrow = Wp3g + cc * 32;
      double accj[3] = {0.0, 0.0, 0.0};
      for (int c2 = 0; c2 < 32; ++c2) {
        double w = (double)wrow[c2];
        #pragma unroll
        for (int j = 0; j < 3; ++j)
          accj[j] += w * (double)x1ls[c2 * 15 + j * 5 + m];
      }
      double acc = 0.0;
      #pragma unroll
      for (int j = 0; j < 3; ++j)
        acc += (double)x1ls[cc * 15 + j * 5 + m] * accj[j];
      ddot[cc * 5 + m] = acc;
    }
  }
  __syncthreads();
  if (l < 32) {
    double best = -1e300; int bi = 0;
    for (int m = 0; m < 5; ++m) { double v = ddot[l * 5 + m]; if (v > best) { best = v; bi = m; } }
    pooled[l * 3 + 0] = x1ls[l * 15 + bi];
    pooled[l * 3 + 1] = x1ls[l * 15 + 5 + bi];
    pooled[l * 3 + 2] = x1ls[l * 15 + 10 + bi];
  }
  __syncthreads();
  if (l < 9) {
    int o2 = l / 3, i = l % 3;
    double a = 0.0;
    for (int c = 0; c < 32; ++c) a += (double)Wh2g[o2 * 32 + c] * (double)pooled[c * 3 + i];
    pkd[i * 3 + o2] = a;
  }
  if (l < 5) scls[l] = phsls[l] + scn[(size_t)s * 5 + l];
  __syncthreads();
  if (l < 5) {
    float nr = sqrtf(scls[0] * scls[0] + scls[1] * scls[1] + scls[2] * scls[2] + scls[3] * scls[3] + scls[4] * scls[4]);
    float v = scls[l] / fmaxf(nr, 1e-12f);
    __syncthreads();
    scls[l] = v;
  } else { __syncthreads(); }
  __syncthreads();
  if (l == 0) {
    unsigned chosen = 0u;
    for (int r = 0; r < 5; ++r) {
      float best = -3.4e38f; int bi = 0;
      for (int n = 0; n < 5; ++n) {
        if ((chosen >> n) & 1u) continue;
        if (scls[n] > best) { best = scls[n]; bi = n; }
      }
      ordls[r] = bi; ssls[r] = best; chosen |= (1u << bi);
    }
  }
  __syncthreads();
  float lp = 0.f;
  if (l < 25) {
    int i = l / 5, j = l % 5;
    lp = -fabsf(scls[i] - ssls[j]) / 0.01f;
  }
  for (int itn = 0; itn < 20; ++itn) {
    if (l < 25) mat[l] = lp;
    __syncthreads();
    if (l < 25) {
      int i = l / 5;
      float m0 = mat[i * 5], m1 = mat[i * 5 + 1], m2 = mat[i * 5 + 2], m3 = mat[i * 5 + 3], m4 = mat[i * 5 + 4];
      float mx = fmaxf(fmaxf(fmaxf(m0, m1), fmaxf(m2, m3)), m4);
      float ssum = __expf(m0 - mx) + __expf(m1 - mx) + __expf(m2 - mx) + __expf(m3 - mx) + __expf(m4 - mx);
      lp -= (mx + __logf(ssum));
    }
    __syncthreads();
    if (l < 25) mat[l] = lp;
    __syncthreads();
    if (l < 25) {
      int j = l % 5;
      float m0 = mat[j], m1 = mat[5 + j], m2 = mat[10 + j], m3 = mat[15 + j], m4 = mat[20 + j];
      float mx = fmaxf(fmaxf(fmaxf(m0, m1), fmaxf(m2, m3)), m4);
      float ssum = __expf(m0 - mx) + __expf(m1 - mx) + __expf(m2 - mx) + __expf(m3 - mx) + __expf(m4 - mx);
      lp -= (mx + __logf(ssum));
    }
    __syncthreads();
  }
  float soft = 0.f;
  if (l < 25) {
    int i = l / 5, j = l % 5;
    soft = __expf(lp);
    float hard = (ordls[j] == i) ? 1.f : 0.f;
    out_hs[(size_t)s * 25 + l] = (hard - soft) + soft;
    mat[l] = fmaxf(soft, 1e-12f);
  }
  __syncthreads();
  if (l < 25) {
    int i = l / 5, j = l % 5;
    float scl = mat[l];
    float colsum = mat[j] + mat[5 + j] + mat[10 + j] + mat[15 + j] + mat[20 + j];
    float rowsum = mat[i * 5] + mat[i * 5 + 1] + mat[i * 5 + 2] + mat[i * 5 + 3] + mat[i * 5 + 4];
    float pc = scl / fmaxf(colsum, 1e-12f);
    float pr = scl / fmaxf(rowsum, 1e-12f);
    float t2 = -pc * fmaxf(__logf(pc), -100.f);
    float t3 = -pr * fmaxf(__logf(pr), -100.f);
    mat2[l] = t2 + t3;
  }
  __syncthreads();
  if (l == 0) {
    float a = 0.f;
    for (int k2 = 0; k2 < 25; ++k2) a += mat2[k2];
    ENT[s] = a;
    double M[9];
    #pragma unroll
    for (int r = 0; r < 9; ++r) M[r] = pkd[r] + (double)rotn[(size_t)s * 9 + r];
    double a0 = M[0], a1 = M[3], a2 = M[6];
    double n0 = sqrt(a0 * a0 + a1 * a1 + a2 * a2) + 1e-12;
    double e10 = a0 / n0, e11 = a1 / n0, e12 = a2 / n0;
    double b0 = M[1], b1 = M[4], b2 = M[7];
    double t1 = e10 * b0 + e11 * b1 + e12 * b2;
    double v20 = b0 - t1 * e10, v21 = b1 - t1 * e11, v22 = b2 - t1 * e12;
    double n2 = sqrt(v20 * v20 + v21 * v21 + v22 * v22) + 1e-12;
    double e20 = v20 / n2, e21 = v21 / n2, e22 = v22 / n2;
    double c0 = M[2], c1 = M[5], c2 = M[8];
    double ta = e10 * c0 + e11 * c1 + e12 * c2;
    double tb = e20 * c0 + e21 * c1 + e22 * c2;
    double v30 = c0 - ta * e10 - tb * e20, v31 = c1 - ta * e11 - tb * e21, v32 = c2 - ta * e12 - tb * e22;
    double n3 = sqrt(v30 * v30 + v31 * v31 + v32 * v32) + 1e-12;
    double e30 = v30 / n3, e31 = v31 / n3, e32 = v32 / n3;
    float* dst = out_ks + (size_t)s * 9;
    dst[0] = (float)e10; dst[1] = (float)e20; dst[2] = (float)e30;
    dst[3] = (float)e11; dst[4] = (float)e21; dst[5] = (float)e31;
    dst[6] = (float)e12; dst[7] = (float)e22; dst[8] = (float)e32;
  }
}

__global__ __launch_bounds__(256) void k_ent_red(const float* ENT, float* outp)
{
  __shared__ double red[256];
  int t = threadIdx.x;
  double a = 0;
  for (int i = t; i < 8192; i += 256) a += (double)ENT[i];
  red[t] = a;
  __syncthreads();
  if (t == 0) {
    double sum = 0;
    for (int k = 0; k < 256; ++k) sum += red[k];
    outp[0] = (float)(sum / 40960.0);
  }
}

// ---------------------------------------------------------------- launch

extern "C" void kernel_launch(void* const* d_in, const int* in_sizes, int n_in,
                              void* d_out, int out_size, void* d_ws, size_t ws_size,
                              hipStream_t stream)
{
  (void)in_sizes; (void)n_in; (void)out_size;
  const float* nf    = (const float*)d_in[0];
  const float* noise = (const float*)d_in[1];
  const float* scn   = (const float*)d_in[2];
  const float* rotn  = (const float*)d_in[3];
  const float* Wf1 = (const float*)d_in[4],  *Wd1 = (const float*)d_in[5];
  const float* g1  = (const float*)d_in[6],  *b1  = (const float*)d_in[7];
  const float* Wf2 = (const float*)d_in[8],  *Wd2 = (const float*)d_in[9];
  const float* g2  = (const float*)d_in[10], *b2  = (const float*)d_in[11];
  const float* Wf3 = (const float*)d_in[12], *Wd3 = (const float*)d_in[13];
  const float* g3  = (const float*)d_in[14], *b3  = (const float*)d_in[15];
  const float* Wp1 = (const float*)d_in[16], *Wp2 = (const float*)d_in[17], *Wp3 = (const float*)d_in[18];
  const float* Ws1f = (const float*)d_in[19], *Ws1d = (const float*)d_in[20];
  const float* gs1  = (const float*)d_in[21], *bs1  = (const float*)d_in[22];
  const float* Ws2f = (const float*)d_in[23], *Ws2d = (const float*)d_in[24];
  const float* gs2  = (const float*)d_in[25], *bs2  = (const float*)d_in[26];
  const float* Wslin = (const float*)d_in[27];
  const float* Wh1   = (const float*)d_in[28];
  const float* bh1   = (const float*)d_in[29];
  const float* Wh2   = (const float*)d_in[30];

  // workspace layout (total 63,997,184 B):
  //   X1, X2, H3, Z1 : 4 x 15,728,640 B
  //   ENT            : 32,768 B   (doubles as RED1 scratch)
  //   ST             : 1,280 B
  //   legacy slot    : 1,048,576 B (PART5 float pairs)
  // PART_main (4 MB doubles) aliases the head of Z1 (dead until k_s1_pass2).
  const size_t SZ = (size_t)8192 * 480;
  if (ws_size < 63997184ull) return;
  float* ws  = (float*)d_ws;
  float* X1  = ws;
  float* X2  = X1 + SZ;
  float* H3  = X2 + SZ;
  float* Z1  = H3 + SZ;
  float* ENT = Z1 + SZ;
  float* ST  = ENT + 8192;
  float* PART5 = ST + 320;
  double* PARTm = (double*)Z1;
  double* RED1  = (double*)ENT;
  float* st1 = ST, *st2 = ST + 64, *st3 = ST + 128, *st4 = ST + 192, *st5 = ST + 256;

  float* out_hs = (float*)d_out;
  float* out_ks = out_hs + 204800;
  float* out_sc = out_hs + 278528;

  dim3 grid(NSAMP), blk(64);
  k_l1_pass1<<<grid, blk, 0, stream>>>(nf, noise, Wf1, PARTm);
  k_red1<<<64, 64, 0, stream>>>(PARTm, RED1, 32);
  k_red2<<<1, 64, 0, stream>>>(RED1, st1, 32, 163840.f);
  k_l1_pass2<<<grid, blk, 0, stream>>>(nf, noise, Wf1, Wd1, g1, b1, st1, Wp1, Wf2, X1, PARTm);
  k_red1<<<64, 64, 0, stream>>>(PARTm, RED1, 32);
  k_red2<<<1, 64, 0, stream>>>(RED1, st2, 32, 163840.f);
  k_l2_pass2<<<grid, blk, 0, stream>>>(X1, Wf2, Wd2, g2, b2, st2, Wp2, Wf3, X2, PARTm);
  k_red1<<<64, 64, 0, stream>>>(PARTm, RED1, 32);
  k_red2<<<1, 64, 0, stream>>>(RED1, st3, 32, 40960.f);
  k_l3_pass2<<<grid, blk, 0, stream>>>(X1, X2, Wf3, Wd3, g3, b3, st3, Ws1f, H3, PARTm);
  k_red1<<<64, 64, 0, stream>>>(PARTm, RED1, 32);
  k_red2<<<1, 64, 0, stream>>>(RED1, st4, 32, 40960.f);
  k_s1_pass2<<<grid, blk, 0, stream>>>(H3, Ws1f, Ws1d, gs1, bs1, st4, Ws2f, Z1, PART5);
  k_red1f<<<64, 64, 0, stream>>>(PART5, RED1, 16);
  k_red2<<<1, 64, 0, stream>>>(RED1, st5, 16, 40960.f);
  k_final<<<grid, blk, 0, stream>>>(Z1, H3, X1, X2, Ws2f, Ws2d, gs2, bs2, st5,
                                    Wslin, Wh1, bh1, Wh2, Wp3, scn, rotn,
                                    out_hs, out_ks, ENT);
  k_ent_red<<<1, 256, 0, stream>>>(ENT, out_sc);
}